// Round 1
// baseline (2310.670 us; speedup 1.0000x reference)
//
#include <hip/hip_runtime.h>
#include <cstddef>

// Problem constants
// CS=8, NV=4, ED=32, VIEWS=3, D=16, KSZ=3, HW=14, CSP=8, KSTATES=4096
// h0: [4096][64][8][8] ; h1: [4096][32][10][10] ; h2: [4096][16][12][12] ; m: [4096][3][14*14]

// ---------------- pre: transpose x -> xT[v][px][b], x2[v][b] ----------------
__global__ __launch_bounds__(256) void pre_kernel(const float* __restrict__ x,
                                                  float* __restrict__ xT,
                                                  float* __restrict__ x2) {
    int v = blockIdx.x;
    int t = threadIdx.x;
    for (int idx = t; idx < 196 * 64; idx += 256) {
        int px = idx >> 6;
        int b  = idx & 63;
        xT[(v * 196 + px) * 64 + b] = x[(b * 3 + v) * 196 + px];
    }
    if (t < 64) {
        int b = t;
        const float* xp = x + (b * 3 + v) * 196;
        float s = 0.f;
        for (int px = 0; px < 196; ++px) s = fmaf(xp[px], xp[px], s);
        x2[v * 64 + b] = s;
    }
}

// ---------------- P[vc][o] = sum_e le[vc][e] * lwv[(vp*32+e)][o] ----------------
__global__ __launch_bounds__(256) void pmat_kernel(const float* __restrict__ le,
                                                   const float* __restrict__ lwv,
                                                   float* __restrict__ P) {
    int o  = blockIdx.x * 256 + threadIdx.x;   // 0..4095
    int vc = blockIdx.y;                        // vp*8 + c, 0..31
    int vp = vc >> 3;
    const float* lep = le + vc * 32;
    float acc = 0.f;
#pragma unroll
    for (int e = 0; e < 32; ++e)
        acc = fmaf(lep[e], lwv[(vp * 32 + e) * 4096 + o], acc);
    P[vc * 4096 + o] = acc;
}

// ---------------- H0T[k][ci][x][y] = lb[o] + sum of 4 P rows ----------------
__global__ __launch_bounds__(256) void h0_kernel(const float* __restrict__ P,
                                                 const float* __restrict__ lbv,
                                                 float* __restrict__ H0T) {
    int t = blockIdx.x * 256 + threadIdx.x;   // 16,777,216 threads
    int k = t >> 12;
    int o = t & 4095;
    int i0 = (k >> 9) & 7, i1 = (k >> 6) & 7, i2 = (k >> 3) & 7, i3 = k & 7;
    float val = lbv[o]
              + P[i0 * 4096 + o]
              + P[(8  + i1) * 4096 + o]
              + P[(16 + i2) * 4096 + o]
              + P[(24 + i3) * 4096 + o];
    int ci = o >> 6;
    int r  = o & 63;
    int yy = r >> 3;   // row
    int xx = r & 7;    // col
    // transposed spatial layout: [ci][col][row]
    H0T[((size_t)k << 12) + (ci << 6) + (xx << 3) + yy] = val;
}

// ---------------- conv1: H0T[k][64][8x][8y] -> H1T[k][32][10x][10y], ELU ----------------
// y[oy][ox] = b + sum_{ci,a,b} x[oy-a][ox-b] * w[ci][co][a][b]
__global__ __launch_bounds__(320) void conv1_kernel(const float* __restrict__ H0T,
                                                    const float* __restrict__ W,   // [64][32][9]
                                                    const float* __restrict__ B,   // [32]
                                                    float* __restrict__ H1T) {
    __shared__ float sX[16 * 12 * 8];    // [ci][col+2 (12)][row (8)]
    __shared__ float sW[16 * 32 * 12];   // [ci][co][12 (9 used)]
    int k = blockIdx.x;
    int t = threadIdx.x;
    int co = t / 10;       // 0..31
    int ox = t % 10;       // 0..9
    float acc[10];
    float bias = B[co];
#pragma unroll
    for (int i = 0; i < 10; ++i) acc[i] = bias;
    const float* h0k = H0T + ((size_t)k << 12);

    for (int ci0 = 0; ci0 < 64; ci0 += 16) {
        for (int idx = t; idx < 16 * 12 * 8; idx += 320) {
            int ci = idx / 96; int r = idx % 96; int c = r / 8; int y = r % 8;
            int xs = c - 2;
            float val = 0.f;
            if (xs >= 0 && xs < 8) val = h0k[(ci0 + ci) * 64 + xs * 8 + y];
            sX[idx] = val;
        }
        for (int idx = t; idx < 16 * 32 * 12; idx += 320) {
            int ci = idx / 384; int r = idx % 384; int c = r / 12; int j = r % 12;
            float val = 0.f;
            if (j < 9) val = W[((ci0 + ci) * 32 + c) * 9 + j];
            sW[idx] = val;
        }
        __syncthreads();

#pragma unroll 2
        for (int ci = 0; ci < 16; ++ci) {
            float xv[3][8];
            const float4* xp = (const float4*)(sX + ci * 96);
#pragma unroll
            for (int b = 0; b < 3; ++b) {
                int c = ox + 2 - b;                 // col+2 index of input col ox-b
                float4 lo = xp[c * 2 + 0];
                float4 hi = xp[c * 2 + 1];
                xv[b][0] = lo.x; xv[b][1] = lo.y; xv[b][2] = lo.z; xv[b][3] = lo.w;
                xv[b][4] = hi.x; xv[b][5] = hi.y; xv[b][6] = hi.z; xv[b][7] = hi.w;
            }
            const float4* wp = (const float4*)(sW + (ci * 32 + co) * 12);
            float4 w0 = wp[0], w1 = wp[1], w2 = wp[2];
            float wv[9] = {w0.x, w0.y, w0.z, w0.w, w1.x, w1.y, w1.z, w1.w, w2.x};
#pragma unroll
            for (int a = 0; a < 3; ++a)
#pragma unroll
                for (int b = 0; b < 3; ++b) {
                    float wgt = wv[a * 3 + b];
#pragma unroll
                    for (int j = 0; j < 8; ++j)      // input row j contributes to oy=a+j
                        acc[a + j] = fmaf(xv[b][j], wgt, acc[a + j]);
                }
        }
        __syncthreads();
    }
    // ELU + store transposed: H1T[k][co][ox][oy]
    float* dst = H1T + (size_t)k * 3200 + (co * 10 + ox) * 10;
#pragma unroll
    for (int oy = 0; oy < 10; ++oy) {
        float v = acc[oy];
        dst[oy] = v > 0.f ? v : expm1f(v);
    }
}

// ---------------- conv2: H1T[k][32][10x][10y] -> H2T[k][16][12x][12y], ELU ----------------
__global__ __launch_bounds__(192) void conv2_kernel(const float* __restrict__ H1T,
                                                    const float* __restrict__ W,   // [32][16][9]
                                                    const float* __restrict__ B,   // [16]
                                                    float* __restrict__ H2T) {
    __shared__ float sX[16 * 14 * 12];   // [ci][col+2 (14)][row (12, 10 valid)]
    __shared__ float sW[16 * 16 * 12];
    int k = blockIdx.x;
    int t = threadIdx.x;
    int co = t / 12;       // 0..15
    int ox = t % 12;       // 0..11
    float acc[12];
    float bias = B[co];
#pragma unroll
    for (int i = 0; i < 12; ++i) acc[i] = bias;
    const float* h1k = H1T + (size_t)k * 3200;

    for (int ci0 = 0; ci0 < 32; ci0 += 16) {
        for (int idx = t; idx < 16 * 14 * 12; idx += 192) {
            int ci = idx / 168; int r = idx % 168; int c = r / 12; int y = r % 12;
            int xs = c - 2;
            float val = 0.f;
            if (xs >= 0 && xs < 10 && y < 10) val = h1k[(ci0 + ci) * 100 + xs * 10 + y];
            sX[idx] = val;
        }
        for (int idx = t; idx < 16 * 16 * 12; idx += 192) {
            int ci = idx / 192; int r = idx % 192; int c = r / 12; int j = r % 12;
            float val = 0.f;
            if (j < 9) val = W[((ci0 + ci) * 16 + c) * 9 + j];
            sW[idx] = val;
        }
        __syncthreads();

#pragma unroll 2
        for (int ci = 0; ci < 16; ++ci) {
            float xv[3][10];
#pragma unroll
            for (int b = 0; b < 3; ++b) {
                int c = ox + 2 - b;
                const float* col = sX + ci * 168 + c * 12;
                float4 p0 = *(const float4*)(col + 0);
                float4 p1 = *(const float4*)(col + 4);
                float2 p2 = *(const float2*)(col + 8);
                xv[b][0] = p0.x; xv[b][1] = p0.y; xv[b][2] = p0.z; xv[b][3] = p0.w;
                xv[b][4] = p1.x; xv[b][5] = p1.y; xv[b][6] = p1.z; xv[b][7] = p1.w;
                xv[b][8] = p2.x; xv[b][9] = p2.y;
            }
            const float4* wp = (const float4*)(sW + (ci * 16 + co) * 12);
            float4 w0 = wp[0], w1 = wp[1], w2 = wp[2];
            float wv[9] = {w0.x, w0.y, w0.z, w0.w, w1.x, w1.y, w1.z, w1.w, w2.x};
#pragma unroll
            for (int a = 0; a < 3; ++a)
#pragma unroll
                for (int b = 0; b < 3; ++b) {
                    float wgt = wv[a * 3 + b];
#pragma unroll
                    for (int j = 0; j < 10; ++j)
                        acc[a + j] = fmaf(xv[b][j], wgt, acc[a + j]);
                }
        }
        __syncthreads();
    }
    float* dst = H2T + (size_t)k * 2304 + (co * 12 + ox) * 12;
#pragma unroll
    for (int oy = 0; oy < 12; ++oy) {
        float v = acc[oy];
        dst[oy] = v > 0.f ? v : expm1f(v);
    }
}

// ---------------- conv3: H2T[k][16][12x][12y] -> M[k][v][196] (no activation) ----------------
__global__ __launch_bounds__(256) void conv3_kernel(const float* __restrict__ H2T,
                                                    const float* __restrict__ W,   // [16][9]
                                                    const float* __restrict__ B,   // [1]
                                                    float* __restrict__ M,
                                                    int v) {
    __shared__ float sX[16 * 16 * 16];   // [ci][col+2 (16)][row+2 (16)]
    __shared__ float sW[16 * 12];
    int k = blockIdx.x;
    int t = threadIdx.x;
    const float* h2k = H2T + (size_t)k * 2304;
    for (int idx = t; idx < 16 * 16 * 16; idx += 256) {
        int ci = idx >> 8; int r = idx & 255; int c = r >> 4; int y = r & 15;
        int xs = c - 2, ys = y - 2;
        float val = 0.f;
        if (xs >= 0 && xs < 12 && ys >= 0 && ys < 12) val = h2k[ci * 144 + xs * 12 + ys];
        sX[idx] = val;
    }
    for (int idx = t; idx < 16 * 12; idx += 256) {
        int ci = idx / 12; int j = idx % 12;
        sW[idx] = (j < 9) ? W[ci * 9 + j] : 0.f;
    }
    __syncthreads();
    if (t < 196) {
        int oy = t / 14;
        int ox = t % 14;
        float acc = B[0];
#pragma unroll 4
        for (int ci = 0; ci < 16; ++ci) {
            const float* xb = sX + ci * 256;
            const float* wb = sW + ci * 12;
#pragma unroll
            for (int a = 0; a < 3; ++a)
#pragma unroll
                for (int b = 0; b < 3; ++b)
                    acc = fmaf(xb[(ox + 2 - b) * 16 + (oy + 2 - a)], wb[a * 3 + b], acc);
        }
        M[((size_t)k * 3 + v) * 196 + t] = acc;
    }
}

// ---------------- final: out[b][k][v] = -0.5*(m2[k,v] + x2[b,v] - 2*cross) ----------------
__global__ __launch_bounds__(192) void final_kernel(const float* __restrict__ M,
                                                    const float* __restrict__ xT,   // [3][196][64]
                                                    const float* __restrict__ x2,   // [3][64]
                                                    float* __restrict__ out) {
    __shared__ float sm[588];
    int k = blockIdx.x;
    int t = threadIdx.x;
    for (int idx = t; idx < 588; idx += 192) sm[idx] = M[(size_t)k * 588 + idx];
    __syncthreads();
    int v = t >> 6;
    int b = t & 63;
    const float* xp = xT + v * 196 * 64 + b;
    const float* mp = sm + v * 196;
    float cross = 0.f, m2 = 0.f;
#pragma unroll 4
    for (int px = 0; px < 196; ++px) {
        float mv = mp[px];
        float xv = xp[px * 64];
        cross = fmaf(mv, xv, cross);
        m2    = fmaf(mv, mv, m2);
    }
    out[((size_t)b * 4096 + k) * 3 + v] = -0.5f * (m2 + x2[v * 64 + b] - 2.f * cross);
}

extern "C" void kernel_launch(void* const* d_in, const int* in_sizes, int n_in,
                              void* d_out, int out_size, void* d_ws, size_t ws_size,
                              hipStream_t stream) {
    const float* x     = (const float*)d_in[0];   // [64][3][14][14]
    const float* le    = (const float*)d_in[1];   // [4][8][32]
    const float* lin_w = (const float*)d_in[2];   // [3][128][4096]
    const float* lin_b = (const float*)d_in[3];   // [3][4096]
    const float* w1    = (const float*)d_in[4];   // [3][64][32][3][3]
    const float* b1    = (const float*)d_in[5];   // [3][32]
    const float* w2    = (const float*)d_in[6];   // [3][32][16][3][3]
    const float* b2    = (const float*)d_in[7];   // [3][16]
    const float* w3    = (const float*)d_in[8];   // [3][16][1][3][3]
    const float* b3    = (const float*)d_in[9];   // [3][1]
    float* out = (float*)d_out;

    float* ws = (float*)d_ws;
    // workspace layout (floats)
    float* xT  = ws;                         // 3*196*64      = 37632
    float* x2  = xT + 37632;                 // 192
    float* P   = x2 + 192;                   // 32*4096       = 131072
    float* M   = P + 131072;                 // 4096*3*196    = 2408448
    float* H0  = M + 2408448;                // 4096*4096     = 16777216  (aliased by H2)
    float* H1  = H0 + 16777216;              // 4096*3200     = 13107200
    float* H2  = H0;                         // 4096*2304 fits in H0's slot (H0 dead by then)

    pre_kernel<<<3, 256, 0, stream>>>(x, xT, x2);

    for (int v = 0; v < 3; ++v) {
        pmat_kernel<<<dim3(16, 32), 256, 0, stream>>>(le, lin_w + (size_t)v * 128 * 4096, P);
        h0_kernel<<<65536, 256, 0, stream>>>(P, lin_b + v * 4096, H0);
        conv1_kernel<<<4096, 320, 0, stream>>>(H0, w1 + v * 64 * 32 * 9, b1 + v * 32, H1);
        conv2_kernel<<<4096, 192, 0, stream>>>(H1, w2 + v * 32 * 16 * 9, b2 + v * 16, H2);
        conv3_kernel<<<4096, 256, 0, stream>>>(H2, w3 + v * 16 * 9, b3 + v, M, v);
    }
    final_kernel<<<4096, 192, 0, stream>>>(M, xT, x2, out);
}

// Round 2
// 958.064 us; speedup vs baseline: 2.4118x; 2.4118x over previous
//
#include <hip/hip_runtime.h>
#include <cstddef>

// Problem constants
// CS=8, NV=4, ED=32, VIEWS=3, D=16, KSZ=3, HW=14, CSP=8, KSTATES=4096
// h1: [4096][32][10][10] ; h2: [4096][16][12][12] ; m: [4096][3][14*14]
//
// Key identity: h0[k] = lb + sum_d P[d][digit_d(k)]  (linear-layer gather trick)
// and conv_t is linear, so  h1_pre[k] = Qb + sum_d Q[d][digit_d(k)]
// where Q rows are conv_t applied to the 32 P rows (+ bias row). conv1 never
// runs per-state.

// ---------------- pre: transpose x -> xT[v][px][b], x2[v][b] ----------------
__global__ __launch_bounds__(256) void pre_kernel(const float* __restrict__ x,
                                                  float* __restrict__ xT,
                                                  float* __restrict__ x2) {
    int v = blockIdx.x;
    int t = threadIdx.x;
    for (int idx = t; idx < 196 * 64; idx += 256) {
        int px = idx >> 6;
        int b  = idx & 63;
        xT[(v * 196 + px) * 64 + b] = x[(b * 3 + v) * 196 + px];
    }
    if (t < 64) {
        int b = t;
        const float* xp = x + (b * 3 + v) * 196;
        float s = 0.f;
        for (int px = 0; px < 196; ++px) s = fmaf(xp[px], xp[px], s);
        x2[v * 64 + b] = s;
    }
}

// ---------------- P[vc][o] = sum_e le[vc][e] * lwv[(vp*32+e)][o] ----------------
__global__ __launch_bounds__(256) void pmat_kernel(const float* __restrict__ le,
                                                   const float* __restrict__ lwv,
                                                   float* __restrict__ P) {
    int o  = blockIdx.x * 256 + threadIdx.x;   // 0..4095
    int vc = blockIdx.y;                        // vp*8 + c, 0..31
    int vp = vc >> 3;
    const float* lep = le + vc * 32;
    float acc = 0.f;
#pragma unroll
    for (int e = 0; e < 32; ++e)
        acc = fmaf(lep[e], lwv[(vp * 32 + e) * 4096 + o], acc);
    P[vc * 4096 + o] = acc;
}

// ---------------- fold1: Q[row][co][ox][oy] = conv_t(P_row or lb)  ----------------
// Q layout matches H1T: o1 = co*100 + ox*10 + oy. Row 32 = conv_t(lb) + b1.
// y[co][oy][ox] = sum_{ci,a,b} x[ci][oy-a][ox-b] * w[ci][co][a][b], x in [ci][8y][8x]
__global__ __launch_bounds__(320) void fold1_kernel(const float* __restrict__ P,     // [32][4096]
                                                    const float* __restrict__ lbv,   // [4096]
                                                    const float* __restrict__ w1v,   // [64][32][9]
                                                    const float* __restrict__ b1v,   // [32]
                                                    float* __restrict__ Q) {         // [33][3200]
    __shared__ float sP[4096];
    int row = blockIdx.x;            // 0..32
    int t = threadIdx.x;
    const float* src = (row < 32) ? (P + row * 4096) : lbv;
    for (int i = t; i < 4096; i += 320) sP[i] = src[i];
    __syncthreads();
    int o1 = blockIdx.y * 320 + t;   // 0..3199
    int co = o1 / 100;
    int r  = o1 % 100;
    int ox = r / 10;
    int oy = r % 10;
    int alo = oy > 7 ? oy - 7 : 0, ahi = oy < 2 ? oy : 2;
    int blo = ox > 7 ? ox - 7 : 0, bhi = ox < 2 ? ox : 2;
    float acc = 0.f;
    for (int ci = 0; ci < 64; ++ci) {
        const float* sp = sP + ci * 64;
        const float* wp = w1v + (ci * 32 + co) * 9;
        for (int a = alo; a <= ahi; ++a) {
            int ybase = (oy - a) * 8;
            for (int b = blo; b <= bhi; ++b)
                acc = fmaf(sp[ybase + (ox - b)], wp[a * 3 + b], acc);
        }
    }
    if (row == 32) acc += b1v[co];
    Q[row * 3200 + o1] = acc;
}

// ---------------- h1: H1T[k][o1] = ELU(Qb[o1] + 4 gathered Q rows) ----------------
__global__ __launch_bounds__(256) void h1_kernel(const float* __restrict__ Q,   // [33][3200]
                                                 float* __restrict__ H1T) {     // [4096][3200]
    int k = blockIdx.x;
    int i0 = (k >> 9) & 7, i1 = (k >> 6) & 7, i2 = (k >> 3) & 7, i3 = k & 7;
    const float4* q0 = (const float4*)(Q + i0 * 3200);
    const float4* q1 = (const float4*)(Q + (8  + i1) * 3200);
    const float4* q2 = (const float4*)(Q + (16 + i2) * 3200);
    const float4* q3 = (const float4*)(Q + (24 + i3) * 3200);
    const float4* qb = (const float4*)(Q + 32 * 3200);
    float4* dst = (float4*)(H1T + (size_t)k * 3200);
    for (int i = threadIdx.x; i < 800; i += 256) {
        float4 a = q0[i], b = q1[i], c = q2[i], d = q3[i], e = qb[i];
        float4 s;
        s.x = a.x + b.x + c.x + d.x + e.x;
        s.y = a.y + b.y + c.y + d.y + e.y;
        s.z = a.z + b.z + c.z + d.z + e.z;
        s.w = a.w + b.w + c.w + d.w + e.w;
        s.x = s.x > 0.f ? s.x : expm1f(s.x);
        s.y = s.y > 0.f ? s.y : expm1f(s.y);
        s.z = s.z > 0.f ? s.z : expm1f(s.z);
        s.w = s.w > 0.f ? s.w : expm1f(s.w);
        dst[i] = s;
    }
}

// ---------------- conv2: H1T[k][32][10x][10y] -> H2T[k][16][12x][12y], ELU ----------------
__global__ __launch_bounds__(192) void conv2_kernel(const float* __restrict__ H1T,
                                                    const float* __restrict__ W,   // [32][16][9]
                                                    const float* __restrict__ B,   // [16]
                                                    float* __restrict__ H2T) {
    __shared__ float sX[16 * 14 * 12];   // [ci][col+2 (14)][row (12, 10 valid)]
    __shared__ float sW[16 * 16 * 12];
    int k = blockIdx.x;
    int t = threadIdx.x;
    int co = t / 12;       // 0..15
    int ox = t % 12;       // 0..11
    float acc[12];
    float bias = B[co];
#pragma unroll
    for (int i = 0; i < 12; ++i) acc[i] = bias;
    const float* h1k = H1T + (size_t)k * 3200;

    for (int ci0 = 0; ci0 < 32; ci0 += 16) {
        for (int idx = t; idx < 16 * 14 * 12; idx += 192) {
            int ci = idx / 168; int r = idx % 168; int c = r / 12; int y = r % 12;
            int xs = c - 2;
            float val = 0.f;
            if (xs >= 0 && xs < 10 && y < 10) val = h1k[(ci0 + ci) * 100 + xs * 10 + y];
            sX[idx] = val;
        }
        for (int idx = t; idx < 16 * 16 * 12; idx += 192) {
            int ci = idx / 192; int r = idx % 192; int c = r / 12; int j = r % 12;
            float val = 0.f;
            if (j < 9) val = W[((ci0 + ci) * 16 + c) * 9 + j];
            sW[idx] = val;
        }
        __syncthreads();

#pragma unroll 2
        for (int ci = 0; ci < 16; ++ci) {
            float xv[3][10];
#pragma unroll
            for (int b = 0; b < 3; ++b) {
                int c = ox + 2 - b;
                const float* col = sX + ci * 168 + c * 12;
                float4 p0 = *(const float4*)(col + 0);
                float4 p1 = *(const float4*)(col + 4);
                float2 p2 = *(const float2*)(col + 8);
                xv[b][0] = p0.x; xv[b][1] = p0.y; xv[b][2] = p0.z; xv[b][3] = p0.w;
                xv[b][4] = p1.x; xv[b][5] = p1.y; xv[b][6] = p1.z; xv[b][7] = p1.w;
                xv[b][8] = p2.x; xv[b][9] = p2.y;
            }
            const float4* wp = (const float4*)(sW + (ci * 16 + co) * 12);
            float4 w0 = wp[0], w1 = wp[1], w2 = wp[2];
            float wv[9] = {w0.x, w0.y, w0.z, w0.w, w1.x, w1.y, w1.z, w1.w, w2.x};
#pragma unroll
            for (int a = 0; a < 3; ++a)
#pragma unroll
                for (int b = 0; b < 3; ++b) {
                    float wgt = wv[a * 3 + b];
#pragma unroll
                    for (int j = 0; j < 10; ++j)
                        acc[a + j] = fmaf(xv[b][j], wgt, acc[a + j]);
                }
        }
        __syncthreads();
    }
    float* dst = H2T + (size_t)k * 2304 + (co * 12 + ox) * 12;
#pragma unroll
    for (int oy = 0; oy < 12; ++oy) {
        float v = acc[oy];
        dst[oy] = v > 0.f ? v : expm1f(v);
    }
}

// ---------------- conv3: H2T[k][16][12x][12y] -> M[k][v][196] (no activation) ----------------
__global__ __launch_bounds__(256) void conv3_kernel(const float* __restrict__ H2T,
                                                    const float* __restrict__ W,   // [16][9]
                                                    const float* __restrict__ B,   // [1]
                                                    float* __restrict__ M,
                                                    int v) {
    __shared__ float sX[16 * 16 * 16];   // [ci][col+2 (16)][row+2 (16)]
    __shared__ float sW[16 * 12];
    int k = blockIdx.x;
    int t = threadIdx.x;
    const float* h2k = H2T + (size_t)k * 2304;
    for (int idx = t; idx < 16 * 16 * 16; idx += 256) {
        int ci = idx >> 8; int r = idx & 255; int c = r >> 4; int y = r & 15;
        int xs = c - 2, ys = y - 2;
        float val = 0.f;
        if (xs >= 0 && xs < 12 && ys >= 0 && ys < 12) val = h2k[ci * 144 + xs * 12 + ys];
        sX[idx] = val;
    }
    for (int idx = t; idx < 16 * 12; idx += 256) {
        int ci = idx / 12; int j = idx % 12;
        sW[idx] = (j < 9) ? W[ci * 9 + j] : 0.f;
    }
    __syncthreads();
    if (t < 196) {
        int oy = t / 14;
        int ox = t % 14;
        float acc = B[0];
#pragma unroll 4
        for (int ci = 0; ci < 16; ++ci) {
            const float* xb = sX + ci * 256;
            const float* wb = sW + ci * 12;
#pragma unroll
            for (int a = 0; a < 3; ++a)
#pragma unroll
                for (int b = 0; b < 3; ++b)
                    acc = fmaf(xb[(ox + 2 - b) * 16 + (oy + 2 - a)], wb[a * 3 + b], acc);
        }
        M[((size_t)k * 3 + v) * 196 + t] = acc;
    }
}

// ---------------- final: out[b][k][v] = -0.5*(m2[k,v] + x2[b,v] - 2*cross) ----------------
__global__ __launch_bounds__(192) void final_kernel(const float* __restrict__ M,
                                                    const float* __restrict__ xT,   // [3][196][64]
                                                    const float* __restrict__ x2,   // [3][64]
                                                    float* __restrict__ out) {
    __shared__ float sm[588];
    int k = blockIdx.x;
    int t = threadIdx.x;
    for (int idx = t; idx < 588; idx += 192) sm[idx] = M[(size_t)k * 588 + idx];
    __syncthreads();
    int v = t >> 6;
    int b = t & 63;
    const float* xp = xT + v * 196 * 64 + b;
    const float* mp = sm + v * 196;
    float cross = 0.f, m2 = 0.f;
#pragma unroll 4
    for (int px = 0; px < 196; ++px) {
        float mv = mp[px];
        float xv = xp[px * 64];
        cross = fmaf(mv, xv, cross);
        m2    = fmaf(mv, mv, m2);
    }
    out[((size_t)b * 4096 + k) * 3 + v] = -0.5f * (m2 + x2[v * 64 + b] - 2.f * cross);
}

extern "C" void kernel_launch(void* const* d_in, const int* in_sizes, int n_in,
                              void* d_out, int out_size, void* d_ws, size_t ws_size,
                              hipStream_t stream) {
    const float* x     = (const float*)d_in[0];   // [64][3][14][14]
    const float* le    = (const float*)d_in[1];   // [4][8][32]
    const float* lin_w = (const float*)d_in[2];   // [3][128][4096]
    const float* lin_b = (const float*)d_in[3];   // [3][4096]
    const float* w1    = (const float*)d_in[4];   // [3][64][32][3][3]
    const float* b1    = (const float*)d_in[5];   // [3][32]
    const float* w2    = (const float*)d_in[6];   // [3][32][16][3][3]
    const float* b2    = (const float*)d_in[7];   // [3][16]
    const float* w3    = (const float*)d_in[8];   // [3][16][1][3][3]
    const float* b3    = (const float*)d_in[9];   // [3][1]
    float* out = (float*)d_out;

    float* ws = (float*)d_ws;
    // workspace layout (floats)
    float* xT  = ws;                         // 3*196*64      = 37632
    float* x2  = xT + 37632;                 // 192
    float* P   = x2 + 192;                   // 32*4096       = 131072
    float* Q   = P + 131072;                 // 33*3200       = 105600
    float* M   = Q + 105600;                 // 4096*3*196    = 2408448
    float* H1  = M + 2408448;                // 4096*3200     = 13107200
    float* H2  = H1 + 13107200;              // 4096*2304     = 9437184

    pre_kernel<<<3, 256, 0, stream>>>(x, xT, x2);

    for (int v = 0; v < 3; ++v) {
        pmat_kernel<<<dim3(16, 32), 256, 0, stream>>>(le, lin_w + (size_t)v * 128 * 4096, P);
        fold1_kernel<<<dim3(33, 10), 320, 0, stream>>>(P, lin_b + v * 4096,
                                                       w1 + v * 64 * 32 * 9, b1 + v * 32, Q);
        h1_kernel<<<4096, 256, 0, stream>>>(Q, H1);
        conv2_kernel<<<4096, 192, 0, stream>>>(H1, w2 + v * 32 * 16 * 9, b2 + v * 16, H2);
        conv3_kernel<<<4096, 256, 0, stream>>>(H2, w3 + v * 16 * 9, b3 + v, M, v);
    }
    final_kernel<<<4096, 192, 0, stream>>>(M, xT, x2, out);
}

// Round 4
// 533.050 us; speedup vs baseline: 4.3348x; 1.7973x over previous
//
#include <hip/hip_runtime.h>
#include <cstddef>

// CS=8 NV=4 ED=32 VIEWS=3 D=16 KSZ=3 HW=14 CSP=8 KSTATES=4096
// Pipeline:
//   P[32][4096]   = per-(slot,code) linear partials            (pmat)
//   Qcl[33][3200] = conv_t1 of P rows (+bias row), channel-last (fold1)
//   Q01/Q23b[64][3200] = pairwise digit sums                    (pair)
//   fused: per (state,view): h1=ELU(Q01+Q23b) -> bf16 LDS ->
//          conv2 via 81x mfma_f32_16x16x32_bf16 -> ELU -> bf16 LDS ->
//          conv3 (VALU) -> M[k][v][196]
//   final: out[b][k][v]
// Spatial layouts are col-major ([col][row]) end-to-end inside the fused
// kernel; the M write converts back to row-major (row*14+col) — this was
// the round-3 bug.

typedef __attribute__((ext_vector_type(8))) short short8;
typedef __attribute__((ext_vector_type(4))) float f32x4;

static __device__ __forceinline__ short f2bf(float f) {
    unsigned u = __builtin_bit_cast(unsigned, f);
    unsigned r = (u + 0x7fffu + ((u >> 16) & 1u)) >> 16;
    return (short)r;
}
static __device__ __forceinline__ float bf2f(short s) {
    unsigned u = ((unsigned)(unsigned short)s) << 16;
    return __builtin_bit_cast(float, u);
}

// ---------------- pre: transpose x -> xT[v][px][b], x2[v][b] ----------------
__global__ __launch_bounds__(256) void pre_kernel(const float* __restrict__ x,
                                                  float* __restrict__ xT,
                                                  float* __restrict__ x2) {
    int v = blockIdx.x;
    int t = threadIdx.x;
    for (int idx = t; idx < 196 * 64; idx += 256) {
        int px = idx >> 6;
        int b  = idx & 63;
        xT[(v * 196 + px) * 64 + b] = x[(b * 3 + v) * 196 + px];
    }
    if (t < 64) {
        int b = t;
        const float* xp = x + (b * 3 + v) * 196;
        float s = 0.f;
        for (int px = 0; px < 196; ++px) s = fmaf(xp[px], xp[px], s);
        x2[v * 64 + b] = s;
    }
}

// ---------------- P[vc][o] = sum_e le[vc][e] * lwv[(vp*32+e)][o] ----------------
__global__ __launch_bounds__(256) void pmat_kernel(const float* __restrict__ le,
                                                   const float* __restrict__ lwv,
                                                   float* __restrict__ P) {
    int o  = blockIdx.x * 256 + threadIdx.x;
    int vc = blockIdx.y;
    int vp = vc >> 3;
    const float* lep = le + vc * 32;
    float acc = 0.f;
#pragma unroll
    for (int e = 0; e < 32; ++e)
        acc = fmaf(lep[e], lwv[(vp * 32 + e) * 4096 + o], acc);
    P[vc * 4096 + o] = acc;
}

// ---------------- fold1: Qcl[row][(ox*10+oy)*32+co] = conv_t1(P_row or lb) ----------------
__global__ __launch_bounds__(320) void fold1_kernel(const float* __restrict__ P,
                                                    const float* __restrict__ lbv,
                                                    const float* __restrict__ w1v,   // [64][32][9]
                                                    const float* __restrict__ b1v,   // [32]
                                                    float* __restrict__ Qcl) {       // [33][3200]
    __shared__ float sP[4096];
    int row = blockIdx.x;            // 0..32
    int t = threadIdx.x;
    const float* src = (row < 32) ? (P + row * 4096) : lbv;
    for (int i = t; i < 4096; i += 320) sP[i] = src[i];
    __syncthreads();
    int o1 = blockIdx.y * 320 + t;   // 0..3199
    int co = o1 / 100;
    int r  = o1 % 100;
    int ox = r / 10;
    int oy = r % 10;
    int alo = oy > 7 ? oy - 7 : 0, ahi = oy < 2 ? oy : 2;
    int blo = ox > 7 ? ox - 7 : 0, bhi = ox < 2 ? ox : 2;
    float acc = 0.f;
    for (int ci = 0; ci < 64; ++ci) {
        const float* sp = sP + ci * 64;
        const float* wp = w1v + (ci * 32 + co) * 9;
        for (int a = alo; a <= ahi; ++a) {
            int ybase = (oy - a) * 8;
            for (int b = blo; b <= bhi; ++b)
                acc = fmaf(sp[ybase + (ox - b)], wp[a * 3 + b], acc);
        }
    }
    if (row == 32) acc += b1v[co];
    Qcl[row * 3200 + (ox * 10 + oy) * 32 + co] = acc;
}

// ---------------- pair: Q01[p]=Q[i0]+Q[8+i1]; Q23b[p]=Q[16+i2]+Q[24+i3]+Qbias ----------------
__global__ __launch_bounds__(256) void pair_kernel(const float* __restrict__ Qcl,
                                                   float* __restrict__ Q01,
                                                   float* __restrict__ Q23b) {
    int p = blockIdx.x;        // 0..63
    int half = blockIdx.y;     // 0 -> Q01, 1 -> Q23b
    if (half == 0) {
        const float* ra = Qcl + (p >> 3) * 3200;
        const float* rb = Qcl + (8 + (p & 7)) * 3200;
        float* dst = Q01 + p * 3200;
        for (int i = threadIdx.x; i < 3200; i += 256) dst[i] = ra[i] + rb[i];
    } else {
        const float* ra = Qcl + (16 + (p >> 3)) * 3200;
        const float* rb = Qcl + (24 + (p & 7)) * 3200;
        const float* rc = Qcl + 32 * 3200;
        float* dst = Q23b + p * 3200;
        for (int i = threadIdx.x; i < 3200; i += 256) dst[i] = ra[i] + rb[i] + rc[i];
    }
}

// ---------------- wfrag: precompute conv2 B-fragments, bf16 ----------------
// B[k=ci][n=co]: lane holds n=lane&15, k=(lane>>4)*8+j
__global__ __launch_bounds__(64) void wfrag_kernel(const float* __restrict__ w2,
                                                   short* __restrict__ Wf) {
    int v = blockIdx.x;
    int lane = threadIdx.x;
    const float* w2v = w2 + v * 32 * 16 * 9;
    int co = lane & 15;
    int cibase = (lane >> 4) * 8;
#pragma unroll
    for (int tap = 0; tap < 9; ++tap)
#pragma unroll
        for (int j = 0; j < 8; ++j)
            Wf[(((v * 9 + tap) * 64 + lane) << 3) + j] =
                f2bf(w2v[((cibase + j) * 16 + co) * 9 + tap]);
}

// ---------------- fused: h1 -> conv2(MFMA) -> conv3 -> M ----------------
__global__ __launch_bounds__(192) void fused_kernel(const float* __restrict__ Q01,   // [3][64][3200]
                                                    const float* __restrict__ Q23b,  // [3][64][3200]
                                                    const short* __restrict__ Wf,    // [3][9][64][8]
                                                    const float* __restrict__ b2,    // [3][16]
                                                    const float* __restrict__ w3,    // [3][16][9]
                                                    const float* __restrict__ b3,    // [3][1]
                                                    float* __restrict__ M) {         // [4096][3][196]
    __shared__ short sH1[14 * 14 * 32];   // [col_p][row_p][ci] bf16, pad=0, valid [2..11]^2
    __shared__ short sH2[16 * 16 * 16];   // [col_p][row_p][co] bf16, pad=0, valid [2..13]^2
    int k = blockIdx.x;
    int v = blockIdx.y;
    int t = threadIdx.x;
    int lane = t & 63;

    // phase 0: zero LDS
    {
        int* z1 = (int*)sH1;
        for (int i = t; i < 14 * 14 * 16; i += 192) z1[i] = 0;
        int* z2 = (int*)sH2;
        for (int i = t; i < 16 * 16 * 8; i += 192) z2[i] = 0;
    }

    // preload conv2 B-fragments + bias (registers, no LDS dependency)
    short8 bfrag[9];
#pragma unroll
    for (int tap = 0; tap < 9; ++tap)
        bfrag[tap] = *(const short8*)(Wf + (((v * 9 + tap) * 64 + lane) << 3));
    float bias2 = b2[v * 16 + (lane & 15)];

    __syncthreads();

    // phase 1: h1 = ELU(Q01[i01] + Q23b[i23]) -> sH1 (channel-last, padded)
    {
        const float* qa = Q01  + ((size_t)v * 64 + (k >> 6)) * 3200;
        const float* qb = Q23b + ((size_t)v * 64 + (k & 63)) * 3200;
        for (int i = t; i < 3200; i += 192) {
            float s = qa[i] + qb[i];
            s = s > 0.f ? s : expm1f(s);
            int pix = i >> 5;               // pix = col*10 + row
            int ci  = i & 31;
            int cx = pix / 10, ry = pix % 10;
            sH1[((cx + 2) * 14 + (ry + 2)) * 32 + ci] = f2bf(s);
        }
    }
    __syncthreads();

    // phase 2: conv2 via MFMA. 9 pixel-tiles x 9 taps. wave w handles tiles w, w+3, w+6.
    {
        int w = t >> 6;
        int g = lane >> 4;         // ci-group
        for (int tile = w; tile < 9; tile += 3) {
            int m = tile * 16 + (lane & 15);      // output pixel 0..143 (col*12+row)
            int cx2 = m / 12, ry2 = m % 12;
            int basemin = (cx2 * 14 + ry2) * 32 + g * 8;   // tap (a=2,b=2)
            f32x4 acc = {bias2, bias2, bias2, bias2};
#pragma unroll
            for (int a = 0; a < 3; ++a)
#pragma unroll
                for (int b = 0; b < 3; ++b) {
                    short8 af = *(const short8*)(sH1 + basemin + ((2 - b) * 14 + (2 - a)) * 32);
                    acc = __builtin_amdgcn_mfma_f32_16x16x32_bf16(af, bfrag[a * 3 + b], acc, 0, 0, 0);
                }
            // ELU + store to sH2. D row = (lane>>4)*4+reg, col = lane&15
            int co = lane & 15;
#pragma unroll
            for (int r = 0; r < 4; ++r) {
                int p = tile * 16 + g * 4 + r;    // p = col*12+row
                int cxp = p / 12, ryp = p % 12;
                float val = acc[r];
                val = val > 0.f ? val : expm1f(val);
                sH2[((cxp + 2) * 16 + (ryp + 2)) * 16 + co] = f2bf(val);
            }
        }
    }
    __syncthreads();

    // phase 3: conv3 (VALU, bf16 reads, fp32 acc) -> M row-major (row*14+col)
    {
        const float* w3v = w3 + v * 16 * 9;
        float bias3 = b3[v];
        for (int o = t; o < 196; o += 192) {
            int ry3 = o / 14;      // output row
            int cx3 = o % 14;      // output col  (sH2's leading dim is col)
            float acc = bias3;
#pragma unroll
            for (int a = 0; a < 3; ++a)
#pragma unroll
                for (int b = 0; b < 3; ++b) {
                    int base = ((cx3 + 2 - b) * 16 + (ry3 + 2 - a)) * 16;
                    const short8* hp = (const short8*)(sH2 + base);
                    short8 lo = hp[0], hi = hp[1];
                    int tap = a * 3 + b;
#pragma unroll
                    for (int j = 0; j < 8; ++j) {
                        acc = fmaf(bf2f(lo[j]), w3v[j * 9 + tap], acc);
                        acc = fmaf(bf2f(hi[j]), w3v[(8 + j) * 9 + tap], acc);
                    }
                }
            M[((size_t)k * 3 + v) * 196 + o] = acc;   // o = row*14+col (row-major)
        }
    }
}

// ---------------- final: out[b][k][v] = -0.5*(m2 + x2 - 2*cross) ----------------
__global__ __launch_bounds__(192) void final_kernel(const float* __restrict__ M,
                                                    const float* __restrict__ xT,   // [3][196][64]
                                                    const float* __restrict__ x2,   // [3][64]
                                                    float* __restrict__ out) {
    __shared__ float sm[588];
    int k = blockIdx.x;
    int t = threadIdx.x;
    for (int idx = t; idx < 588; idx += 192) sm[idx] = M[(size_t)k * 588 + idx];
    __syncthreads();
    int v = t >> 6;
    int b = t & 63;
    const float* xp = xT + v * 196 * 64 + b;
    const float* mp = sm + v * 196;
    float cross = 0.f, m2 = 0.f;
#pragma unroll 4
    for (int px = 0; px < 196; ++px) {
        float mv = mp[px];
        float xv = xp[px * 64];
        cross = fmaf(mv, xv, cross);
        m2    = fmaf(mv, mv, m2);
    }
    out[((size_t)b * 4096 + k) * 3 + v] = -0.5f * (m2 + x2[v * 64 + b] - 2.f * cross);
}

extern "C" void kernel_launch(void* const* d_in, const int* in_sizes, int n_in,
                              void* d_out, int out_size, void* d_ws, size_t ws_size,
                              hipStream_t stream) {
    const float* x     = (const float*)d_in[0];
    const float* le    = (const float*)d_in[1];
    const float* lin_w = (const float*)d_in[2];
    const float* lin_b = (const float*)d_in[3];
    const float* w1    = (const float*)d_in[4];
    const float* b1    = (const float*)d_in[5];
    const float* w2    = (const float*)d_in[6];
    const float* b2    = (const float*)d_in[7];
    const float* w3    = (const float*)d_in[8];
    const float* b3    = (const float*)d_in[9];
    float* out = (float*)d_out;

    float* ws = (float*)d_ws;
    float* xT   = ws;                        // 37632
    float* x2   = xT + 37632;                // 192
    float* P    = x2 + 192;                  // 131072
    float* Qcl  = P + 131072;                // 33*3200 = 105600
    float* Q01  = Qcl + 105600;              // 3*64*3200 = 614400
    float* Q23b = Q01 + 614400;              // 614400
    float* M    = Q23b + 614400;             // 4096*3*196 = 2408448
    short* Wf   = (short*)(M + 2408448);     // 3*9*64*8 shorts = 13824

    pre_kernel<<<3, 256, 0, stream>>>(x, xT, x2);

    for (int v = 0; v < 3; ++v) {
        pmat_kernel<<<dim3(16, 32), 256, 0, stream>>>(le, lin_w + (size_t)v * 128 * 4096, P);
        fold1_kernel<<<dim3(33, 10), 320, 0, stream>>>(P, lin_b + v * 4096,
                                                       w1 + v * 64 * 32 * 9, b1 + v * 32, Qcl);
        pair_kernel<<<dim3(64, 2), 256, 0, stream>>>(Qcl, Q01 + (size_t)v * 204800,
                                                     Q23b + (size_t)v * 204800);
    }
    wfrag_kernel<<<3, 64, 0, stream>>>(w2, Wf);

    fused_kernel<<<dim3(4096, 3), 192, 0, stream>>>(Q01, Q23b, Wf, b2, w3, b3, M);

    final_kernel<<<4096, 192, 0, stream>>>(M, xT, x2, out);
}

// Round 5
// 350.859 us; speedup vs baseline: 6.5858x; 1.5193x over previous
//
#include <hip/hip_runtime.h>
#include <cstddef>

// CS=8 NV=4 ED=32 VIEWS=3 D=16 KSZ=3 HW=14 CSP=8 KSTATES=4096
// Pipeline:
//   P3[3][32][4096]    linear partials per (view,slot,code)       (pmat)
//   Qcl3[3][33][3200]  conv_t1 of P rows (+bias row), chan-last   (fold1)
//   Q01/Q23b[3][64][3200] pairwise digit sums                     (pair)
//   fused per (state,view): h1=ELU(Q01+Q23b) -> bf16 LDS (stride-40) ->
//     conv2 = 81x mfma_f32_16x16x32_bf16 -> ELU -> bf16 LDS (24/392) ->
//     conv3 (VALU, 4-acc ILP) -> M[k][v][196] row-major
//   final: out[b][k][v]
// LDS strides chosen so consecutive-pixel lanes land 2-way max on banks
// (20p mod 32 all-distinct for sH1; col delta = 4 banks for sH2).

typedef __attribute__((ext_vector_type(8))) short short8;
typedef __attribute__((ext_vector_type(4))) float f32x4;

static __device__ __forceinline__ short f2bf(float f) {
    unsigned u = __builtin_bit_cast(unsigned, f);
    unsigned r = (u + 0x7fffu + ((u >> 16) & 1u)) >> 16;
    return (short)r;
}
static __device__ __forceinline__ float bf2f(short s) {
    unsigned u = ((unsigned)(unsigned short)s) << 16;
    return __builtin_bit_cast(float, u);
}
static __device__ __forceinline__ float elu(float s) {
    float e = __expf(s) - 1.0f;     // v_exp-based, ~5 inst vs libm expm1f
    return s > 0.f ? s : e;
}

// ---------------- pre: transpose x -> xT[v][px][b], x2[v][b] ----------------
__global__ __launch_bounds__(256) void pre_kernel(const float* __restrict__ x,
                                                  float* __restrict__ xT,
                                                  float* __restrict__ x2) {
    int v = blockIdx.x;
    int t = threadIdx.x;
    for (int idx = t; idx < 196 * 64; idx += 256) {
        int px = idx >> 6;
        int b  = idx & 63;
        xT[(v * 196 + px) * 64 + b] = x[(b * 3 + v) * 196 + px];
    }
    if (t < 64) {
        int b = t;
        const float* xp = x + (b * 3 + v) * 196;
        float s = 0.f;
        for (int px = 0; px < 196; ++px) s = fmaf(xp[px], xp[px], s);
        x2[v * 64 + b] = s;
    }
}

// ---------------- pmat: P3[v][vc][o], all views ----------------
__global__ __launch_bounds__(256) void pmat_kernel(const float* __restrict__ le,
                                                   const float* __restrict__ lin_w,
                                                   float* __restrict__ P3) {
    int o  = blockIdx.x * 256 + threadIdx.x;
    int vc = blockIdx.y;
    int v  = blockIdx.z;
    int vp = vc >> 3;
    const float* lwv = lin_w + (size_t)v * 128 * 4096;
    const float* lep = le + vc * 32;
    float acc = 0.f;
#pragma unroll
    for (int e = 0; e < 32; ++e)
        acc = fmaf(lep[e], lwv[(vp * 32 + e) * 4096 + o], acc);
    P3[((size_t)v * 32 + vc) * 4096 + o] = acc;
}

// ---------------- fold1: Qcl3[v][row][(ox*10+oy)*32+co], all views ----------------
__global__ __launch_bounds__(320) void fold1_kernel(const float* __restrict__ P3,
                                                    const float* __restrict__ lin_b,
                                                    const float* __restrict__ w1,
                                                    const float* __restrict__ b1,
                                                    float* __restrict__ Qcl3) {
    __shared__ float sP[4096];
    int row = blockIdx.x;            // 0..32
    int v   = blockIdx.z;
    int t = threadIdx.x;
    const float* src = (row < 32) ? (P3 + ((size_t)v * 32 + row) * 4096)
                                  : (lin_b + v * 4096);
    for (int i = t; i < 4096; i += 320) sP[i] = src[i];
    __syncthreads();
    const float* w1v = w1 + (size_t)v * 64 * 32 * 9;
    int o1 = blockIdx.y * 320 + t;   // 0..3199
    int co = o1 / 100;
    int r  = o1 % 100;
    int ox = r / 10;
    int oy = r % 10;
    int alo = oy > 7 ? oy - 7 : 0, ahi = oy < 2 ? oy : 2;
    int blo = ox > 7 ? ox - 7 : 0, bhi = ox < 2 ? ox : 2;
    float acc = 0.f;
    for (int ci = 0; ci < 64; ++ci) {
        const float* sp = sP + ci * 64;
        const float* wp = w1v + (ci * 32 + co) * 9;
        for (int a = alo; a <= ahi; ++a) {
            int ybase = (oy - a) * 8;
            for (int b = blo; b <= bhi; ++b)
                acc = fmaf(sp[ybase + (ox - b)], wp[a * 3 + b], acc);
        }
    }
    if (row == 32) acc += b1[v * 32 + co];
    Qcl3[(size_t)v * 105600 + row * 3200 + (ox * 10 + oy) * 32 + co] = acc;
}

// ---------------- pair: Q01/Q23b, all views, float4 ----------------
__global__ __launch_bounds__(256) void pair_kernel(const float* __restrict__ Qcl3,
                                                   float* __restrict__ Q01,
                                                   float* __restrict__ Q23b) {
    int p = blockIdx.x;        // 0..63
    int half = blockIdx.y;
    int v = blockIdx.z;
    const float4* base = (const float4*)(Qcl3 + (size_t)v * 105600);
    if (half == 0) {
        const float4* ra = base + (p >> 3) * 800;
        const float4* rb = base + (8 + (p & 7)) * 800;
        float4* dst = (float4*)(Q01 + (size_t)v * 204800 + p * 3200);
        for (int i = threadIdx.x; i < 800; i += 256) {
            float4 a = ra[i], b = rb[i];
            dst[i] = float4{a.x + b.x, a.y + b.y, a.z + b.z, a.w + b.w};
        }
    } else {
        const float4* ra = base + (16 + (p >> 3)) * 800;
        const float4* rb = base + (24 + (p & 7)) * 800;
        const float4* rc = base + 32 * 800;
        float4* dst = (float4*)(Q23b + (size_t)v * 204800 + p * 3200);
        for (int i = threadIdx.x; i < 800; i += 256) {
            float4 a = ra[i], b = rb[i], c = rc[i];
            dst[i] = float4{a.x + b.x + c.x, a.y + b.y + c.y,
                            a.z + b.z + c.z, a.w + b.w + c.w};
        }
    }
}

// ---------------- wfrag: conv2 B-fragments, bf16 ----------------
__global__ __launch_bounds__(64) void wfrag_kernel(const float* __restrict__ w2,
                                                   short* __restrict__ Wf) {
    int v = blockIdx.x;
    int lane = threadIdx.x;
    const float* w2v = w2 + v * 32 * 16 * 9;
    int co = lane & 15;
    int cibase = (lane >> 4) * 8;
#pragma unroll
    for (int tap = 0; tap < 9; ++tap)
#pragma unroll
        for (int j = 0; j < 8; ++j)
            Wf[(((v * 9 + tap) * 64 + lane) << 3) + j] =
                f2bf(w2v[((cibase + j) * 16 + co) * 9 + tap]);
}

// ---------------- fused: h1 -> conv2(MFMA) -> conv3 -> M ----------------
__global__ __launch_bounds__(192) void fused_kernel(const float* __restrict__ Q01,   // [3][64][3200]
                                                    const float* __restrict__ Q23b,  // [3][64][3200]
                                                    const short* __restrict__ Wf,    // [3][9][64][8]
                                                    const float* __restrict__ b2,    // [3][16]
                                                    const float* __restrict__ w3,    // [3][16][9]
                                                    const float* __restrict__ b3,    // [3][1]
                                                    float* __restrict__ M) {         // [4096][3][196]
    __shared__ alignas(16) short sH1[196 * 40];  // [pix=c*14+r][40 (32 used)] bf16
    __shared__ alignas(16) short sH2[16 * 392];  // c*392 + r*24 + co, bf16
    __shared__ float sW3[144];                   // w3[ci][tap]
    int k = blockIdx.x;
    int v = blockIdx.y;
    int t = threadIdx.x;
    int lane = t & 63;
    int g = lane >> 4;

    // preload conv2 B-fragments + bias (registers only)
    short8 bfrag[9];
#pragma unroll
    for (int tap = 0; tap < 9; ++tap)
        bfrag[tap] = *(const short8*)(Wf + (((v * 9 + tap) * 64 + lane) << 3));
    float bias2 = b2[v * 16 + (lane & 15)];

    // zero ONLY pad regions (disjoint from phase-1/2 interior writes)
    for (int pix = t; pix < 196; pix += 192) {
        int c = pix / 14, r = pix % 14;
        if (c < 2 || c >= 12 || r < 2 || r >= 12) {
            int4* z = (int4*)(sH1 + pix * 40);
            z[0] = int4{0,0,0,0}; z[1] = int4{0,0,0,0};
            z[2] = int4{0,0,0,0}; z[3] = int4{0,0,0,0};
        }
    }
    for (int pix = t; pix < 256; pix += 192) {
        int c = pix >> 4, r = pix & 15;
        if (c < 2 || c >= 14 || r < 2 || r >= 14) {
            int4* z = (int4*)(sH2 + c * 392 + r * 24);
            z[0] = int4{0,0,0,0}; z[1] = int4{0,0,0,0};
        }
    }
    if (t < 144) sW3[t] = w3[v * 144 + t];

    // phase 1: h1 = ELU(Q01 + Q23b) -> sH1 (float4 in, short4 out, no div)
    {
        const float4* qa = (const float4*)(Q01  + ((size_t)v * 64 + (k >> 6)) * 3200);
        const float4* qb = (const float4*)(Q23b + ((size_t)v * 64 + (k & 63)) * 3200);
        int ci4 = (t & 7) * 4;          // constant across iterations (192 = 24*8)
        int pix = t >> 3;               // 0..23, steps by 24
        int cx = 0, ry = pix;
        while (ry >= 10) { ry -= 10; ++cx; }
        for (int i = t; i < 800; i += 192) {
            float4 a = qa[i], b = qb[i];
            short4 o;
            o.x = f2bf(elu(a.x + b.x));
            o.y = f2bf(elu(a.y + b.y));
            o.z = f2bf(elu(a.z + b.z));
            o.w = f2bf(elu(a.w + b.w));
            *(short4*)(sH1 + ((cx + 2) * 14 + (ry + 2)) * 40 + ci4) = o;
            cx += 2; ry += 4;                      // pix += 24
            if (ry >= 10) { ry -= 10; ++cx; }
        }
    }
    __syncthreads();

    // phase 2: conv2 via MFMA. wave w handles pixel-tiles w, w+3, w+6.
    {
        int w = t >> 6;
        for (int tile = w; tile < 9; tile += 3) {
            int m = tile * 16 + (lane & 15);       // out pixel = col*12+row
            int cx2 = m / 12, ry2 = m % 12;
            const short* basemin = sH1 + (cx2 * 14 + ry2) * 40 + g * 8;
            f32x4 acc = {bias2, bias2, bias2, bias2};
#pragma unroll
            for (int a = 0; a < 3; ++a)
#pragma unroll
                for (int b = 0; b < 3; ++b) {
                    short8 af = *(const short8*)(basemin + ((2 - b) * 14 + (2 - a)) * 40);
                    acc = __builtin_amdgcn_mfma_f32_16x16x32_bf16(af, bfrag[a * 3 + b], acc, 0, 0, 0);
                }
            int p0 = tile * 16 + g * 4;
            int cxp = p0 / 12, ryp = p0 % 12;
            int co = lane & 15;
#pragma unroll
            for (int r = 0; r < 4; ++r) {
                sH2[(cxp + 2) * 392 + (ryp + 2) * 24 + co] = f2bf(elu(acc[r]));
                ++ryp; if (ryp == 12) { ryp = 0; ++cxp; }
            }
        }
    }
    __syncthreads();

    // phase 3: conv3, 4 independent accumulators, bf16 LDS reads
    {
        float bias3 = b3[v];
        for (int o = t; o < 196; o += 192) {
            int ry3 = o / 14, cx3 = o % 14;
            float a0 = bias3, a1 = 0.f, a2 = 0.f, a3 = 0.f;
#pragma unroll
            for (int a = 0; a < 3; ++a)
#pragma unroll
                for (int b = 0; b < 3; ++b) {
                    const short* base = sH2 + (cx3 + 2 - b) * 392 + (ry3 + 2 - a) * 24;
                    short8 lo = *(const short8*)(base);
                    short8 hi = *(const short8*)(base + 8);
                    int tap = a * 3 + b;
#pragma unroll
                    for (int j = 0; j < 4; ++j) {
                        a0 = fmaf(bf2f(lo[2*j]),     sW3[(2*j)*9 + tap],     a0);
                        a1 = fmaf(bf2f(lo[2*j+1]),   sW3[(2*j+1)*9 + tap],   a1);
                        a2 = fmaf(bf2f(hi[2*j]),     sW3[(8+2*j)*9 + tap],   a2);
                        a3 = fmaf(bf2f(hi[2*j+1]),   sW3[(8+2*j+1)*9 + tap], a3);
                    }
                }
            M[((size_t)k * 3 + v) * 196 + o] = (a0 + a1) + (a2 + a3);
        }
    }
}

// ---------------- final: out[b][k][v] = -0.5*(m2 + x2 - 2*cross) ----------------
__global__ __launch_bounds__(192) void final_kernel(const float* __restrict__ M,
                                                    const float* __restrict__ xT,   // [3][196][64]
                                                    const float* __restrict__ x2,   // [3][64]
                                                    float* __restrict__ out) {
    __shared__ float sm[588];
    int k = blockIdx.x;
    int t = threadIdx.x;
    for (int idx = t; idx < 588; idx += 192) sm[idx] = M[(size_t)k * 588 + idx];
    __syncthreads();
    int v = t >> 6;
    int b = t & 63;
    const float* xp = xT + v * 196 * 64 + b;
    const float* mp = sm + v * 196;
    float cross = 0.f, m2 = 0.f;
#pragma unroll 4
    for (int px = 0; px < 196; ++px) {
        float mv = mp[px];
        float xv = xp[px * 64];
        cross = fmaf(mv, xv, cross);
        m2    = fmaf(mv, mv, m2);
    }
    out[((size_t)b * 4096 + k) * 3 + v] = -0.5f * (m2 + x2[v * 64 + b] - 2.f * cross);
}

extern "C" void kernel_launch(void* const* d_in, const int* in_sizes, int n_in,
                              void* d_out, int out_size, void* d_ws, size_t ws_size,
                              hipStream_t stream) {
    const float* x     = (const float*)d_in[0];
    const float* le    = (const float*)d_in[1];
    const float* lin_w = (const float*)d_in[2];
    const float* lin_b = (const float*)d_in[3];
    const float* w1    = (const float*)d_in[4];
    const float* b1    = (const float*)d_in[5];
    const float* w2    = (const float*)d_in[6];
    const float* b2    = (const float*)d_in[7];
    const float* w3    = (const float*)d_in[8];
    const float* b3    = (const float*)d_in[9];
    float* out = (float*)d_out;

    float* ws = (float*)d_ws;
    float* xT   = ws;                        // 37632
    float* x2   = xT + 37632;                // 192
    float* P3   = x2 + 192;                  // 3*32*4096 = 393216
    float* Qcl3 = P3 + 393216;               // 3*33*3200 = 316800
    float* Q01  = Qcl3 + 316800;             // 3*64*3200 = 614400
    float* Q23b = Q01 + 614400;              // 614400
    float* M    = Q23b + 614400;             // 4096*3*196 = 2408448
    short* Wf   = (short*)(M + 2408448);     // 3*9*64*8 shorts

    pre_kernel<<<3, 256, 0, stream>>>(x, xT, x2);
    pmat_kernel<<<dim3(16, 32, 3), 256, 0, stream>>>(le, lin_w, P3);
    fold1_kernel<<<dim3(33, 10, 3), 320, 0, stream>>>(P3, lin_b, w1, b1, Qcl3);
    pair_kernel<<<dim3(64, 2, 3), 256, 0, stream>>>(Qcl3, Q01, Q23b);
    wfrag_kernel<<<3, 64, 0, stream>>>(w2, Wf);
    fused_kernel<<<dim3(4096, 3), 192, 0, stream>>>(Q01, Q23b, Wf, b2, w3, b3, M);
    final_kernel<<<4096, 192, 0, stream>>>(M, xT, x2, out);
}

// Round 6
// 249.348 us; speedup vs baseline: 9.2669x; 1.4071x over previous
//
#include <hip/hip_runtime.h>
#include <cstddef>

// CS=8 NV=4 ED=32 VIEWS=3 D=16 KSZ=3 HW=14 CSP=8 KSTATES=4096
// Pipeline:
//   P3[3][32][4096]     linear partials per (view,slot,code)      (pmat)
//   Qcl3[3][33][3200]   conv_t1 of P rows (+bias row), chan-last  (fold1, LDS-staged)
//   Q01/Q23b[3][64][3200] pairwise digit sums                     (pair)
//   fused per (state,view), 256 thr: h1=ELU(Q01+Q23b) -> f16 LDS (stride-40)
//     -> conv2 = 81x mfma_f32_16x16x32_f16 (dual acc) -> ELU -> f16 LDS (24/392)
//     -> conv3 via v_dot2_f32_f16 -> M[k][v][196] row-major
//   final: out[b][k][v]

typedef __attribute__((ext_vector_type(8))) short short8;
typedef __attribute__((ext_vector_type(4))) float f32x4;
typedef _Float16 half8v __attribute__((ext_vector_type(8)));
typedef _Float16 half4v __attribute__((ext_vector_type(4)));
typedef _Float16 half2v __attribute__((ext_vector_type(2)));

static __device__ __forceinline__ float elu(float s) {
    float e = __expf(s) - 1.0f;
    return s > 0.f ? s : e;
}
static __device__ __forceinline__ float dot2acc(int hpair, int wpair, float acc) {
#if __has_builtin(__builtin_amdgcn_fdot2)
    return __builtin_amdgcn_fdot2(__builtin_bit_cast(half2v, hpair),
                                  __builtin_bit_cast(half2v, wpair), acc, false);
#else
    half2v h = __builtin_bit_cast(half2v, hpair);
    half2v w = __builtin_bit_cast(half2v, wpair);
    acc = fmaf((float)h.x, (float)w.x, acc);
    return fmaf((float)h.y, (float)w.y, acc);
#endif
}

// ---------------- pre: transpose x -> xT[v][px][b], x2[v][b] ----------------
__global__ __launch_bounds__(256) void pre_kernel(const float* __restrict__ x,
                                                  float* __restrict__ xT,
                                                  float* __restrict__ x2) {
    int v = blockIdx.x;
    int t = threadIdx.x;
    for (int idx = t; idx < 196 * 64; idx += 256) {
        int px = idx >> 6;
        int b  = idx & 63;
        xT[(v * 196 + px) * 64 + b] = x[(b * 3 + v) * 196 + px];
    }
    if (t < 64) {
        int b = t;
        const float* xp = x + (b * 3 + v) * 196;
        float s = 0.f;
        for (int px = 0; px < 196; ++px) s = fmaf(xp[px], xp[px], s);
        x2[v * 64 + b] = s;
    }
}

// ---------------- pmat: P3[v][vc][o], all views ----------------
__global__ __launch_bounds__(256) void pmat_kernel(const float* __restrict__ le,
                                                   const float* __restrict__ lin_w,
                                                   float* __restrict__ P3) {
    int o  = blockIdx.x * 256 + threadIdx.x;
    int vc = blockIdx.y;
    int v  = blockIdx.z;
    int vp = vc >> 3;
    const float* lwv = lin_w + (size_t)v * 128 * 4096;
    const float* lep = le + vc * 32;
    float acc = 0.f;
#pragma unroll
    for (int e = 0; e < 32; ++e)
        acc = fmaf(lep[e], lwv[(vp * 32 + e) * 4096 + o], acc);
    P3[((size_t)v * 32 + vc) * 4096 + o] = acc;
}

// ---------------- fold1 (LDS-staged): Qcl3[v][row][(ox*10+oy)*32+co] ----------------
__global__ __launch_bounds__(320) void fold1_kernel(const float* __restrict__ P3,
                                                    const float* __restrict__ lin_b,
                                                    const float* __restrict__ w1,
                                                    const float* __restrict__ b1,
                                                    float* __restrict__ Qcl3) {
    __shared__ float sPt[64 * 144];     // [ci][x_pad 12][y_pad 12], zero-padded
    __shared__ float sW[16 * 32 * 9];   // ci-chunk of 16
    int row = blockIdx.x;               // 0..32
    int v   = blockIdx.y;               // 0..2
    int t = threadIdx.x;
    const float* src = (row < 32) ? (P3 + ((size_t)v * 32 + row) * 4096)
                                  : (lin_b + v * 4096);
    float4* zp = (float4*)sPt;
    for (int i = t; i < 2304; i += 320) zp[i] = float4{0.f, 0.f, 0.f, 0.f};
    __syncthreads();
    for (int i = t; i < 4096; i += 320) {
        int ci = i >> 6, r = i & 63, y = r >> 3, x = r & 7;
        sPt[ci * 144 + (x + 2) * 12 + (y + 2)] = src[i];
    }
    const float* w1v = w1 + (size_t)v * 64 * 32 * 9;
    int co = t / 10, ox = t % 10;
    float acc[10];
#pragma unroll
    for (int i = 0; i < 10; ++i) acc[i] = 0.f;

    for (int c0 = 0; c0 < 4; ++c0) {
        __syncthreads();   // first pass also covers sPt fill
        for (int i = t; i < 4608; i += 320) sW[i] = w1v[c0 * 4608 + i];
        __syncthreads();
#pragma unroll 2
        for (int ci = 0; ci < 16; ++ci) {
            const float* xp = sPt + (c0 * 16 + ci) * 144;
            const float* wp = sW + (ci * 32 + co) * 9;
            float wv[9];
#pragma unroll
            for (int j = 0; j < 9; ++j) wv[j] = wp[j];
#pragma unroll
            for (int b = 0; b < 3; ++b) {
                const float* colp = xp + (ox + 2 - b) * 12;
                float4 c0v = *(const float4*)(colp);
                float4 c1v = *(const float4*)(colp + 4);
                float4 c2v = *(const float4*)(colp + 8);
                float cv[12] = {c0v.x, c0v.y, c0v.z, c0v.w,
                                c1v.x, c1v.y, c1v.z, c1v.w,
                                c2v.x, c2v.y, c2v.z, c2v.w};
#pragma unroll
                for (int a = 0; a < 3; ++a) {
                    float wgt = wv[a * 3 + b];
#pragma unroll
                    for (int oy = 0; oy < 10; ++oy)
                        acc[oy] = fmaf(cv[oy + 2 - a], wgt, acc[oy]);
                }
            }
        }
    }
    float bb = (row == 32) ? b1[v * 32 + co] : 0.f;
    float* dst = Qcl3 + (size_t)v * 105600 + row * 3200;
#pragma unroll
    for (int oy = 0; oy < 10; ++oy)
        dst[(ox * 10 + oy) * 32 + co] = acc[oy] + bb;
}

// ---------------- pair: Q01/Q23b, all views, float4 ----------------
__global__ __launch_bounds__(256) void pair_kernel(const float* __restrict__ Qcl3,
                                                   float* __restrict__ Q01,
                                                   float* __restrict__ Q23b) {
    int p = blockIdx.x;
    int half = blockIdx.y;
    int v = blockIdx.z;
    const float4* base = (const float4*)(Qcl3 + (size_t)v * 105600);
    if (half == 0) {
        const float4* ra = base + (p >> 3) * 800;
        const float4* rb = base + (8 + (p & 7)) * 800;
        float4* dst = (float4*)(Q01 + (size_t)v * 204800 + p * 3200);
        for (int i = threadIdx.x; i < 800; i += 256) {
            float4 a = ra[i], b = rb[i];
            dst[i] = float4{a.x + b.x, a.y + b.y, a.z + b.z, a.w + b.w};
        }
    } else {
        const float4* ra = base + (16 + (p >> 3)) * 800;
        const float4* rb = base + (24 + (p & 7)) * 800;
        const float4* rc = base + 32 * 800;
        float4* dst = (float4*)(Q23b + (size_t)v * 204800 + p * 3200);
        for (int i = threadIdx.x; i < 800; i += 256) {
            float4 a = ra[i], b = rb[i], c = rc[i];
            dst[i] = float4{a.x + b.x + c.x, a.y + b.y + c.y,
                            a.z + b.z + c.z, a.w + b.w + c.w};
        }
    }
}

// ---------------- wfrag: conv2 B-fragments, f16 ----------------
__global__ __launch_bounds__(64) void wfrag_kernel(const float* __restrict__ w2,
                                                   short* __restrict__ Wf) {
    int v = blockIdx.x;
    int lane = threadIdx.x;
    const float* w2v = w2 + v * 32 * 16 * 9;
    int co = lane & 15;
    int cibase = (lane >> 4) * 8;
#pragma unroll
    for (int tap = 0; tap < 9; ++tap)
#pragma unroll
        for (int j = 0; j < 8; ++j) {
            _Float16 h = (_Float16)w2v[((cibase + j) * 16 + co) * 9 + tap];
            Wf[(((v * 9 + tap) * 64 + lane) << 3) + j] = __builtin_bit_cast(short, h);
        }
}

// ---------------- fused: h1 -> conv2(MFMA f16) -> conv3(dot2) -> M ----------------
__global__ __launch_bounds__(256) void fused_kernel(const float* __restrict__ Q01,   // [3][64][3200]
                                                    const float* __restrict__ Q23b,  // [3][64][3200]
                                                    const short* __restrict__ Wf,    // [3][9][64][8]
                                                    const float* __restrict__ b2,    // [3][16]
                                                    const float* __restrict__ w3,    // [3][16][9]
                                                    const float* __restrict__ b3,    // [3][1]
                                                    float* __restrict__ M) {         // [4096][3][196]
    __shared__ alignas(16) short sH1[196 * 40];  // [pix=c*14+r][40 (32 used)] f16
    __shared__ alignas(16) short sH2[16 * 392];  // c*392 + r*24 + co, f16
    __shared__ int sW3p[72];                     // [tap][ci-pair] packed half2
    int k = blockIdx.x;
    int v = blockIdx.y;
    int t = threadIdx.x;
    int lane = t & 63;
    int g = lane >> 4;

    // preload conv2 B-fragments + bias (registers only)
    half8v bfrag[9];
#pragma unroll
    for (int tap = 0; tap < 9; ++tap)
        bfrag[tap] = *(const half8v*)(const void*)(Wf + (((v * 9 + tap) * 64 + lane) << 3));
    float bias2 = b2[v * 16 + (lane & 15)];

    // zero ONLY pad regions (disjoint from interior writes)
    for (int pix = t; pix < 196; pix += 256) {
        int c = pix / 14, r = pix % 14;
        if (c < 2 || c >= 12 || r < 2 || r >= 12) {
            int4* z = (int4*)(sH1 + pix * 40);
            z[0] = int4{0,0,0,0}; z[1] = int4{0,0,0,0};
            z[2] = int4{0,0,0,0}; z[3] = int4{0,0,0,0};
        }
    }
    for (int pix = t; pix < 256; pix += 256) {
        int c = pix >> 4, r = pix & 15;
        if (c < 2 || c >= 14 || r < 2 || r >= 14) {
            int4* z = (int4*)(sH2 + c * 392 + r * 24);
            z[0] = int4{0,0,0,0}; z[1] = int4{0,0,0,0};
        }
    }
    if (t < 72) {
        int tap = t / 8, j = t % 8;
        half2v p = {(_Float16)w3[v * 144 + (2 * j) * 9 + tap],
                    (_Float16)w3[v * 144 + (2 * j + 1) * 9 + tap]};
        sW3p[t] = __builtin_bit_cast(int, p);
    }

    // phase 1: h1 = ELU(Q01 + Q23b) -> sH1 (f16, no div in loop)
    {
        const float4* qa = (const float4*)(Q01  + ((size_t)v * 64 + (k >> 6)) * 3200);
        const float4* qb = (const float4*)(Q23b + ((size_t)v * 64 + (k & 63)) * 3200);
        int ci4 = (t & 7) * 4;
        int pix = t >> 3;               // 0..31, steps by 32
        int cx = pix / 10, ry = pix % 10;
        for (int i = t; i < 800; i += 256) {
            float4 a = qa[i], b = qb[i];
            half4v o = {(_Float16)elu(a.x + b.x), (_Float16)elu(a.y + b.y),
                        (_Float16)elu(a.z + b.z), (_Float16)elu(a.w + b.w)};
            *(half4v*)(void*)(sH1 + ((cx + 2) * 14 + (ry + 2)) * 40 + ci4) = o;
            cx += 3; ry += 2;           // pix += 32
            if (ry >= 10) { ry -= 10; ++cx; }
        }
    }
    __syncthreads();

    // phase 2: conv2 via MFMA f16, dual accumulators. wave w: tiles w, w+4, w+8.
    {
        int w = t >> 6;
        for (int tile = w; tile < 9; tile += 4) {
            int m = tile * 16 + (lane & 15);       // out pixel = col*12+row
            int cx2 = m / 12, ry2 = m % 12;
            const short* basemin = sH1 + (cx2 * 14 + ry2) * 40 + g * 8;
            f32x4 acc0 = {bias2, bias2, bias2, bias2};
            f32x4 acc1 = {0.f, 0.f, 0.f, 0.f};
#pragma unroll
            for (int a = 0; a < 3; ++a)
#pragma unroll
                for (int b = 0; b < 3; ++b) {
                    half8v af = *(const half8v*)(const void*)(basemin + ((2 - b) * 14 + (2 - a)) * 40);
                    int idx = a * 3 + b;
                    if (idx & 1)
                        acc1 = __builtin_amdgcn_mfma_f32_16x16x32_f16(af, bfrag[idx], acc1, 0, 0, 0);
                    else
                        acc0 = __builtin_amdgcn_mfma_f32_16x16x32_f16(af, bfrag[idx], acc0, 0, 0, 0);
                }
            int p0 = tile * 16 + g * 4;
            int cxp = p0 / 12, ryp = p0 % 12;
            int co = lane & 15;
#pragma unroll
            for (int r = 0; r < 4; ++r) {
                _Float16 h = (_Float16)elu(acc0[r] + acc1[r]);
                sH2[(cxp + 2) * 392 + (ryp + 2) * 24 + co] = __builtin_bit_cast(short, h);
                ++ryp; if (ryp == 12) { ryp = 0; ++cxp; }
            }
        }
    }
    __syncthreads();

    // phase 3: conv3 via v_dot2_f32_f16, single pass (196 <= 256)
    if (t < 196) {
        float bias3 = b3[v];
        int ry3 = t / 14, cx3 = t % 14;
        float a0 = bias3, a1 = 0.f, a2 = 0.f, a3 = 0.f;
#pragma unroll
        for (int a = 0; a < 3; ++a)
#pragma unroll
            for (int b = 0; b < 3; ++b) {
                const short* base = sH2 + (cx3 + 2 - b) * 392 + (ry3 + 2 - a) * 24;
                int4 lo = *(const int4*)(const void*)(base);
                int4 hi = *(const int4*)(const void*)(base + 8);
                const int* wp = sW3p + (a * 3 + b) * 8;
                a0 = dot2acc(lo.x, wp[0], a0);
                a1 = dot2acc(lo.y, wp[1], a1);
                a2 = dot2acc(lo.z, wp[2], a2);
                a3 = dot2acc(lo.w, wp[3], a3);
                a0 = dot2acc(hi.x, wp[4], a0);
                a1 = dot2acc(hi.y, wp[5], a1);
                a2 = dot2acc(hi.z, wp[6], a2);
                a3 = dot2acc(hi.w, wp[7], a3);
            }
        M[((size_t)k * 3 + v) * 196 + t] = (a0 + a1) + (a2 + a3);
    }
}

// ---------------- final: out[b][k][v] = -0.5*(m2 + x2 - 2*cross) ----------------
__global__ __launch_bounds__(192) void final_kernel(const float* __restrict__ M,
                                                    const float* __restrict__ xT,   // [3][196][64]
                                                    const float* __restrict__ x2,   // [3][64]
                                                    float* __restrict__ out) {
    __shared__ float sm[588];
    int k = blockIdx.x;
    int t = threadIdx.x;
    for (int idx = t; idx < 588; idx += 192) sm[idx] = M[(size_t)k * 588 + idx];
    __syncthreads();
    int v = t >> 6;
    int b = t & 63;
    const float* xp = xT + v * 196 * 64 + b;
    const float* mp = sm + v * 196;
    float cross = 0.f, m2 = 0.f;
#pragma unroll 4
    for (int px = 0; px < 196; ++px) {
        float mv = mp[px];
        float xv = xp[px * 64];
        cross = fmaf(mv, xv, cross);
        m2    = fmaf(mv, mv, m2);
    }
    out[((size_t)b * 4096 + k) * 3 + v] = -0.5f * (m2 + x2[v * 64 + b] - 2.f * cross);
}

extern "C" void kernel_launch(void* const* d_in, const int* in_sizes, int n_in,
                              void* d_out, int out_size, void* d_ws, size_t ws_size,
                              hipStream_t stream) {
    const float* x     = (const float*)d_in[0];
    const float* le    = (const float*)d_in[1];
    const float* lin_w = (const float*)d_in[2];
    const float* lin_b = (const float*)d_in[3];
    const float* w1    = (const float*)d_in[4];
    const float* b1    = (const float*)d_in[5];
    const float* w2    = (const float*)d_in[6];
    const float* b2    = (const float*)d_in[7];
    const float* w3    = (const float*)d_in[8];
    const float* b3    = (const float*)d_in[9];
    float* out = (float*)d_out;

    float* ws = (float*)d_ws;
    float* xT   = ws;                        // 37632
    float* x2   = xT + 37632;                // 192
    float* P3   = x2 + 192;                  // 3*32*4096 = 393216
    float* Qcl3 = P3 + 393216;               // 3*33*3200 = 316800
    float* Q01  = Qcl3 + 316800;             // 3*64*3200 = 614400
    float* Q23b = Q01 + 614400;              // 614400
    float* M    = Q23b + 614400;             // 4096*3*196 = 2408448
    short* Wf   = (short*)(M + 2408448);     // 3*9*64*8 shorts

    pre_kernel<<<3, 256, 0, stream>>>(x, xT, x2);
    pmat_kernel<<<dim3(16, 32, 3), 256, 0, stream>>>(le, lin_w, P3);
    fold1_kernel<<<dim3(33, 3), 320, 0, stream>>>(P3, lin_b, w1, b1, Qcl3);
    pair_kernel<<<dim3(64, 2, 3), 256, 0, stream>>>(Qcl3, Q01, Q23b);
    wfrag_kernel<<<3, 64, 0, stream>>>(w2, Wf);
    fused_kernel<<<dim3(4096, 3), 256, 0, stream>>>(Q01, Q23b, Wf, b2, w3, b3, M);
    final_kernel<<<4096, 192, 0, stream>>>(M, xT, x2, out);
}

// Round 7
// 209.251 us; speedup vs baseline: 11.0426x; 1.1916x over previous
//
#include <hip/hip_runtime.h>
#include <cstddef>

// CS=8 NV=4 ED=32 VIEWS=3 D=16 KSZ=3 HW=14 CSP=8 KSTATES=4096
// Pipeline:
//   P3[3][32][4096]    linear partials                         (pmat)
//   Qcl3[3][33][3200]  conv_t1 of P rows (+bias row), ci-split atomics (fold1)
//   fused per (state,view), 256 thr: h1=ELU(sum of 4 Q rows + bias row)
//     -> f16 LDS -> conv2 = 81x mfma_f32_16x16x32_f16 -> ELU -> f16 LDS
//     -> conv3 via v_dot2_f32_f16 -> Mh[v][k][224] f16 + m2[v][k]
//   gemm_final: cross = Mh x xB via MFMA f16; out = cross -.5(m2+x2)

typedef __attribute__((ext_vector_type(4))) float f32x4;
typedef _Float16 half8v __attribute__((ext_vector_type(8)));
typedef _Float16 half4v __attribute__((ext_vector_type(4)));
typedef _Float16 half2v __attribute__((ext_vector_type(2)));

static __device__ __forceinline__ float elu(float s) {
    float e = __expf(s) - 1.0f;
    return s > 0.f ? s : e;
}
static __device__ __forceinline__ float dot2acc(int hpair, int wpair, float acc) {
#if __has_builtin(__builtin_amdgcn_fdot2)
    return __builtin_amdgcn_fdot2(__builtin_bit_cast(half2v, hpair),
                                  __builtin_bit_cast(half2v, wpair), acc, false);
#else
    half2v h = __builtin_bit_cast(half2v, hpair);
    half2v w = __builtin_bit_cast(half2v, wpair);
    acc = fmaf((float)h.x, (float)w.x, acc);
    return fmaf((float)h.y, (float)w.y, acc);
#endif
}

// ---------------- pre: x2[v][b]; xB fragments for the final GEMM ----------------
// xB[v][nb][s][lane][j] = f16 x[b=nb*16+(lane&15)][px=s*32+(lane>>4)*8+j]
__global__ __launch_bounds__(256) void pre_kernel(const float* __restrict__ x,
                                                  float* __restrict__ x2,
                                                  short* __restrict__ xB) {
    int v = blockIdx.x;
    int t = threadIdx.x;
    short* xBv = xB + v * 14336;
    for (int idx = t; idx < 14336; idx += 256) {
        int j    = idx & 7;
        int lane = (idx >> 3) & 63;
        int rest = idx >> 9;
        int s    = rest % 7;
        int nb   = rest / 7;
        int px = s * 32 + ((lane >> 4) << 3) + j;
        int b  = nb * 16 + (lane & 15);
        float val = (px < 196) ? x[(b * 3 + v) * 196 + px] : 0.f;
        _Float16 h = (_Float16)val;
        xBv[idx] = __builtin_bit_cast(short, h);
    }
    if (t < 64) {
        int b = t;
        const float* xp = x + (b * 3 + v) * 196;
        float s = 0.f;
        for (int px = 0; px < 196; ++px) s = fmaf(xp[px], xp[px], s);
        x2[v * 64 + b] = s;
    }
}

// ---------------- pmat: P3[v][vc][o] ----------------
__global__ __launch_bounds__(256) void pmat_kernel(const float* __restrict__ le,
                                                   const float* __restrict__ lin_w,
                                                   float* __restrict__ P3) {
    int o  = blockIdx.x * 256 + threadIdx.x;
    int vc = blockIdx.y;
    int v  = blockIdx.z;
    int vp = vc >> 3;
    const float* lwv = lin_w + (size_t)v * 128 * 4096;
    const float* lep = le + vc * 32;
    float acc = 0.f;
#pragma unroll
    for (int e = 0; e < 32; ++e)
        acc = fmaf(lep[e], lwv[(vp * 32 + e) * 4096 + o], acc);
    P3[((size_t)v * 32 + vc) * 4096 + o] = acc;
}

// ---------------- fold1 (ci-split, atomic accumulate into zeroed Qcl3) ----------------
__global__ __launch_bounds__(320) void fold1_kernel(const float* __restrict__ P3,
                                                    const float* __restrict__ lin_b,
                                                    const float* __restrict__ w1,
                                                    const float* __restrict__ b1,
                                                    float* __restrict__ Qcl3) {
    __shared__ float sPt[64 * 144];     // [ci][x_pad 12][y_pad 12], zero-padded
    __shared__ float sW[16 * 32 * 9];
    int row = blockIdx.x;               // 0..32
    int v   = blockIdx.y;               // 0..2
    int z   = blockIdx.z;               // 0..1  ci-half
    int t = threadIdx.x;
    const float* src = (row < 32) ? (P3 + ((size_t)v * 32 + row) * 4096)
                                  : (lin_b + v * 4096);
    float4* zp = (float4*)sPt;
    for (int i = t; i < 2304; i += 320) zp[i] = float4{0.f, 0.f, 0.f, 0.f};
    __syncthreads();
    for (int i = t; i < 4096; i += 320) {
        int ci = i >> 6, r = i & 63, y = r >> 3, xx = r & 7;
        sPt[ci * 144 + (xx + 2) * 12 + (y + 2)] = src[i];
    }
    const float* w1v = w1 + (size_t)v * 64 * 32 * 9;
    int co = t / 10, ox = t % 10;
    float acc[10];
#pragma unroll
    for (int i = 0; i < 10; ++i) acc[i] = 0.f;

    for (int c0 = z * 2; c0 < z * 2 + 2; ++c0) {
        __syncthreads();   // first pass also covers sPt fill
        for (int i = t; i < 4608; i += 320) sW[i] = w1v[c0 * 4608 + i];
        __syncthreads();
#pragma unroll 2
        for (int ci = 0; ci < 16; ++ci) {
            const float* xp = sPt + (c0 * 16 + ci) * 144;
            const float* wp = sW + (ci * 32 + co) * 9;
            float wv[9];
#pragma unroll
            for (int j = 0; j < 9; ++j) wv[j] = wp[j];
#pragma unroll
            for (int b = 0; b < 3; ++b) {
                const float* colp = xp + (ox + 2 - b) * 12;
                float4 c0v = *(const float4*)(colp);
                float4 c1v = *(const float4*)(colp + 4);
                float4 c2v = *(const float4*)(colp + 8);
                float cv[12] = {c0v.x, c0v.y, c0v.z, c0v.w,
                                c1v.x, c1v.y, c1v.z, c1v.w,
                                c2v.x, c2v.y, c2v.z, c2v.w};
#pragma unroll
                for (int a = 0; a < 3; ++a) {
                    float wgt = wv[a * 3 + b];
#pragma unroll
                    for (int oy = 0; oy < 10; ++oy)
                        acc[oy] = fmaf(cv[oy + 2 - a], wgt, acc[oy]);
                }
            }
        }
    }
    float bb = (z == 0 && row == 32) ? b1[v * 32 + co] : 0.f;
    float* dst = Qcl3 + (size_t)v * 105600 + row * 3200;
#pragma unroll
    for (int oy = 0; oy < 10; ++oy)
        atomicAdd(&dst[(ox * 10 + oy) * 32 + co], acc[oy] + bb);
}

// ---------------- wfrag: conv2 B-fragments, f16 ----------------
__global__ __launch_bounds__(64) void wfrag_kernel(const float* __restrict__ w2,
                                                   short* __restrict__ Wf) {
    int v = blockIdx.x;
    int lane = threadIdx.x;
    const float* w2v = w2 + v * 32 * 16 * 9;
    int co = lane & 15;
    int cibase = (lane >> 4) * 8;
#pragma unroll
    for (int tap = 0; tap < 9; ++tap)
#pragma unroll
        for (int j = 0; j < 8; ++j) {
            _Float16 h = (_Float16)w2v[((cibase + j) * 16 + co) * 9 + tap];
            Wf[(((v * 9 + tap) * 64 + lane) << 3) + j] = __builtin_bit_cast(short, h);
        }
}

// ---------------- fused: h1 -> conv2(MFMA f16) -> conv3(dot2) -> Mh,m2 ----------------
__global__ __launch_bounds__(256) void fused_kernel(const float* __restrict__ Qcl3,  // [3][33][3200]
                                                    const short* __restrict__ Wf,    // [3][9][64][8]
                                                    const float* __restrict__ b2,
                                                    const float* __restrict__ w3,    // [3][16][9]
                                                    const float* __restrict__ b3,
                                                    short* __restrict__ Mh,          // [3][4096][224] f16
                                                    float* __restrict__ m2g) {       // [3][4096]
    __shared__ alignas(16) short sH1[196 * 40];  // [pix=c*14+r][40 (32 used)] f16
    __shared__ alignas(16) short sH2[16 * 392];  // c*392 + r*24 + co, f16
    __shared__ int sW3p[72];                     // [tap][ci-pair] packed half2
    __shared__ float sM2;
    int k = blockIdx.x;
    int v = blockIdx.y;
    int t = threadIdx.x;
    int lane = t & 63;
    int g = lane >> 4;

    half8v bfrag[9];
#pragma unroll
    for (int tap = 0; tap < 9; ++tap)
        bfrag[tap] = *(const half8v*)(const void*)(Wf + (((v * 9 + tap) * 64 + lane) << 3));
    float bias2 = b2[v * 16 + (lane & 15)];

    if (t == 0) sM2 = 0.f;
    for (int pix = t; pix < 196; pix += 256) {
        int c = pix / 14, r = pix % 14;
        if (c < 2 || c >= 12 || r < 2 || r >= 12) {
            int4* z = (int4*)(sH1 + pix * 40);
            z[0] = int4{0,0,0,0}; z[1] = int4{0,0,0,0};
            z[2] = int4{0,0,0,0}; z[3] = int4{0,0,0,0};
        }
    }
    {
        int pix = t;
        int c = pix >> 4, r = pix & 15;
        if (c < 2 || c >= 14 || r < 2 || r >= 14) {
            int4* z = (int4*)(sH2 + c * 392 + r * 24);
            z[0] = int4{0,0,0,0}; z[1] = int4{0,0,0,0};
        }
    }
    if (t < 72) {
        int tap = t / 8, j = t % 8;
        half2v p = {(_Float16)w3[v * 144 + (2 * j) * 9 + tap],
                    (_Float16)w3[v * 144 + (2 * j + 1) * 9 + tap]};
        sW3p[t] = __builtin_bit_cast(int, p);
    }

    // phase 1: h1 = ELU(q0+q1+q2+q3+qb) -> sH1 (f16)
    {
        const float* Qv = Qcl3 + (size_t)v * 105600;
        const float4* q0 = (const float4*)(Qv + ((k >> 9) & 7) * 3200);
        const float4* q1 = (const float4*)(Qv + (8  + ((k >> 6) & 7)) * 3200);
        const float4* q2 = (const float4*)(Qv + (16 + ((k >> 3) & 7)) * 3200);
        const float4* q3 = (const float4*)(Qv + (24 + (k & 7)) * 3200);
        const float4* qb = (const float4*)(Qv + 32 * 3200);
        int ci4 = (t & 7) * 4;
        int pix = t >> 3;               // steps by 32
        int cx = pix / 10, ry = pix % 10;
        for (int i = t; i < 800; i += 256) {
            float4 a = q0[i], b = q1[i], c = q2[i], d = q3[i], e = qb[i];
            float sx = a.x + b.x + c.x + d.x + e.x;
            float sy = a.y + b.y + c.y + d.y + e.y;
            float sz = a.z + b.z + c.z + d.z + e.z;
            float sw = a.w + b.w + c.w + d.w + e.w;
            half4v o = {(_Float16)elu(sx), (_Float16)elu(sy),
                        (_Float16)elu(sz), (_Float16)elu(sw)};
            *(half4v*)(void*)(sH1 + ((cx + 2) * 14 + (ry + 2)) * 40 + ci4) = o;
            cx += 3; ry += 2;
            if (ry >= 10) { ry -= 10; ++cx; }
        }
    }
    __syncthreads();

    // phase 2: conv2 via MFMA f16, dual accumulators
    {
        int w = t >> 6;
        for (int tile = w; tile < 9; tile += 4) {
            int m = tile * 16 + (lane & 15);
            int cx2 = m / 12, ry2 = m % 12;
            const short* basemin = sH1 + (cx2 * 14 + ry2) * 40 + g * 8;
            f32x4 acc0 = {bias2, bias2, bias2, bias2};
            f32x4 acc1 = {0.f, 0.f, 0.f, 0.f};
#pragma unroll
            for (int a = 0; a < 3; ++a)
#pragma unroll
                for (int b = 0; b < 3; ++b) {
                    half8v af = *(const half8v*)(const void*)(basemin + ((2 - b) * 14 + (2 - a)) * 40);
                    int idx = a * 3 + b;
                    if (idx & 1)
                        acc1 = __builtin_amdgcn_mfma_f32_16x16x32_f16(af, bfrag[idx], acc1, 0, 0, 0);
                    else
                        acc0 = __builtin_amdgcn_mfma_f32_16x16x32_f16(af, bfrag[idx], acc0, 0, 0, 0);
                }
            int p0 = tile * 16 + g * 4;
            int cxp = p0 / 12, ryp = p0 % 12;
            int co = lane & 15;
#pragma unroll
            for (int r = 0; r < 4; ++r) {
                _Float16 h = (_Float16)elu(acc0[r] + acc1[r]);
                sH2[(cxp + 2) * 392 + (ryp + 2) * 24 + co] = __builtin_bit_cast(short, h);
                ++ryp; if (ryp == 12) { ryp = 0; ++cxp; }
            }
        }
    }
    __syncthreads();

    // phase 3: conv3 via v_dot2_f32_f16 -> Mh f16 + m2 reduction
    {
        float mval = 0.f;
        if (t < 196) {
            float bias3 = b3[v];
            int ry3 = t / 14, cx3 = t % 14;
            float a0 = bias3, a1 = 0.f, a2 = 0.f, a3 = 0.f;
#pragma unroll
            for (int a = 0; a < 3; ++a)
#pragma unroll
                for (int b = 0; b < 3; ++b) {
                    const short* base = sH2 + (cx3 + 2 - b) * 392 + (ry3 + 2 - a) * 24;
                    int4 lo = *(const int4*)(const void*)(base);
                    int4 hi = *(const int4*)(const void*)(base + 8);
                    const int* wp = sW3p + (a * 3 + b) * 8;
                    a0 = dot2acc(lo.x, wp[0], a0);
                    a1 = dot2acc(lo.y, wp[1], a1);
                    a2 = dot2acc(lo.z, wp[2], a2);
                    a3 = dot2acc(lo.w, wp[3], a3);
                    a0 = dot2acc(hi.x, wp[4], a0);
                    a1 = dot2acc(hi.y, wp[5], a1);
                    a2 = dot2acc(hi.z, wp[6], a2);
                    a3 = dot2acc(hi.w, wp[7], a3);
                }
            mval = (a0 + a1) + (a2 + a3);
        }
        if (t < 224) {
            _Float16 h = (_Float16)mval;
            Mh[((size_t)v * 4096 + k) * 224 + t] = __builtin_bit_cast(short, h);
        }
        float sq = mval * mval;
#pragma unroll
        for (int off = 32; off; off >>= 1) sq += __shfl_down(sq, off, 64);
        if (lane == 0) atomicAdd(&sM2, sq);
        __syncthreads();
        if (t == 0) m2g[(size_t)v * 4096 + k] = sM2;
    }
}

// ---------------- gemm_final: cross via MFMA; out[b][k][v] ----------------
__global__ __launch_bounds__(256) void gemm_final_kernel(const short* __restrict__ Mh,   // [3][4096][224]
                                                         const short* __restrict__ xB,   // [3][4][7][64][8]
                                                         const float* __restrict__ m2g,  // [3][4096]
                                                         const float* __restrict__ x2g,  // [3][64]
                                                         float* __restrict__ out) {      // [64][4096][3]
    __shared__ float sC[3 * 64 * 17];
    __shared__ float sM2t[48];
    int t = threadIdx.x, lane = t & 63, nb = t >> 6;
    int k0 = blockIdx.x * 16;
    if (t < 48) {
        int v = t % 3, kk = t / 3;
        sM2t[kk * 3 + v] = m2g[(size_t)v * 4096 + k0 + kk];
    }
    int mrow = lane & 15;
    int g = lane >> 4;
#pragma unroll
    for (int v = 0; v < 3; ++v) {
        f32x4 acc = {0.f, 0.f, 0.f, 0.f};
        const short* abase = Mh + ((size_t)v * 4096 + k0 + mrow) * 224 + g * 8;
        const short* bbase = xB + (((v * 4 + nb) * 7) * 64 + lane) * 8;
#pragma unroll
        for (int s = 0; s < 7; ++s) {
            half8v af = *(const half8v*)(const void*)(abase + s * 32);
            half8v bf = *(const half8v*)(const void*)(bbase + s * 512);
            acc = __builtin_amdgcn_mfma_f32_16x16x32_f16(af, bf, acc, 0, 0, 0);
        }
        int b = nb * 16 + mrow;     // D col = lane&15
#pragma unroll
        for (int r = 0; r < 4; ++r)
            sC[(v * 64 + b) * 17 + g * 4 + r] = acc[r];
    }
    __syncthreads();
    int b = t >> 2, q = t & 3;
    float x2v0 = x2g[b], x2v1 = x2g[64 + b], x2v2 = x2g[128 + b];
    float buf[12];
#pragma unroll
    for (int i = 0; i < 4; ++i) {
        int kk = q * 4 + i;
        buf[i * 3 + 0] = sC[(0 * 64 + b) * 17 + kk] - 0.5f * (sM2t[kk * 3 + 0] + x2v0);
        buf[i * 3 + 1] = sC[(1 * 64 + b) * 17 + kk] - 0.5f * (sM2t[kk * 3 + 1] + x2v1);
        buf[i * 3 + 2] = sC[(2 * 64 + b) * 17 + kk] - 0.5f * (sM2t[kk * 3 + 2] + x2v2);
    }
    float* dst = out + ((size_t)b * 4096 + k0) * 3 + q * 12;
    *(float4*)(dst)     = float4{buf[0], buf[1], buf[2],  buf[3]};
    *(float4*)(dst + 4) = float4{buf[4], buf[5], buf[6],  buf[7]};
    *(float4*)(dst + 8) = float4{buf[8], buf[9], buf[10], buf[11]};
}

extern "C" void kernel_launch(void* const* d_in, const int* in_sizes, int n_in,
                              void* d_out, int out_size, void* d_ws, size_t ws_size,
                              hipStream_t stream) {
    const float* x     = (const float*)d_in[0];
    const float* le    = (const float*)d_in[1];
    const float* lin_w = (const float*)d_in[2];
    const float* lin_b = (const float*)d_in[3];
    const float* w1    = (const float*)d_in[4];
    const float* b1    = (const float*)d_in[5];
    const float* w2    = (const float*)d_in[6];
    const float* b2    = (const float*)d_in[7];
    const float* w3    = (const float*)d_in[8];
    const float* b3    = (const float*)d_in[9];
    float* out = (float*)d_out;

    float* ws = (float*)d_ws;
    // workspace (floats):
    float* x2g  = ws;                        // 192
    short* xB   = (short*)(ws + 192);        // 3*4*7*64*8 halfs = 21504 floats
    float* P3   = ws + 21696;                // 393216
    float* Qcl3 = ws + 414912;               // 316800
    short* Mh   = (short*)(ws + 731712);     // 3*4096*224 halfs = 1376256 floats
    float* m2g  = ws + 2107968;              // 12288
    short* Wf   = (short*)(ws + 2120256);    // 13824 halfs

    pre_kernel<<<3, 256, 0, stream>>>(x, x2g, xB);
    pmat_kernel<<<dim3(16, 32, 3), 256, 0, stream>>>(le, lin_w, P3);
    hipMemsetAsync(Qcl3, 0, 316800 * sizeof(float), stream);
    fold1_kernel<<<dim3(33, 3, 2), 320, 0, stream>>>(P3, lin_b, w1, b1, Qcl3);
    wfrag_kernel<<<3, 64, 0, stream>>>(w2, Wf);
    fused_kernel<<<dim3(4096, 3), 256, 0, stream>>>(Qcl3, Wf, b2, w3, b3, Mh, m2g);
    gemm_final_kernel<<<256, 256, 0, stream>>>(Mh, xB, m2g, x2g, out);
}

// Round 8
// 199.739 us; speedup vs baseline: 11.5685x; 1.0476x over previous
//
#include <hip/hip_runtime.h>
#include <cstddef>

// CS=8 NV=4 ED=32 VIEWS=3 D=16 KSZ=3 HW=14 CSP=8 KSTATES=4096
// Pipeline:
//   P3[3][32][4096]      linear partials                        (pmat)
//   Qa/Qb[3][33][3200]   conv_t1 of P rows (+bias row), ci-halves (fold1)
//   Q01/Q23b[3][64][3200] pairwise digit sums of (Qa+Qb)        (pair)
//   fused per (state,view), 256 thr: h1=ELU(Q01+Q23b) -> f16 LDS
//     -> conv2 = 81x mfma_f32_16x16x32_f16 -> ELU -> f16 LDS
//     -> conv3 via v_dot2_f32_f16 -> Mh[v][k][224] f16 + m2[v][k]
//   gemm_final: cross = Mh x xB via MFMA f16; out = cross -.5(m2+x2)

typedef __attribute__((ext_vector_type(4))) float f32x4;
typedef _Float16 half8v __attribute__((ext_vector_type(8)));
typedef _Float16 half4v __attribute__((ext_vector_type(4)));
typedef _Float16 half2v __attribute__((ext_vector_type(2)));

static __device__ __forceinline__ float elu(float s) {
    float e = __expf(s) - 1.0f;
    return s > 0.f ? s : e;
}
static __device__ __forceinline__ float dot2acc(int hpair, int wpair, float acc) {
#if __has_builtin(__builtin_amdgcn_fdot2)
    return __builtin_amdgcn_fdot2(__builtin_bit_cast(half2v, hpair),
                                  __builtin_bit_cast(half2v, wpair), acc, false);
#else
    half2v h = __builtin_bit_cast(half2v, hpair);
    half2v w = __builtin_bit_cast(half2v, wpair);
    acc = fmaf((float)h.x, (float)w.x, acc);
    return fmaf((float)h.y, (float)w.y, acc);
#endif
}

// ---------------- pre: xB fragments (y=0..3), x2 (y=4), Wf (y=5) ----------------
__global__ __launch_bounds__(256) void pre_kernel(const float* __restrict__ x,
                                                  float* __restrict__ x2,
                                                  short* __restrict__ xB,
                                                  const float* __restrict__ w2,
                                                  short* __restrict__ Wf) {
    int v = blockIdx.x;
    int part = blockIdx.y;
    int t = threadIdx.x;
    if (part < 4) {
        int nb = part;
        short* xBv = xB + v * 14336 + nb * 3584;
        for (int idx = t; idx < 3584; idx += 256) {
            int j = idx & 7, lane = (idx >> 3) & 63, s = idx >> 9;
            int px = s * 32 + ((lane >> 4) << 3) + j;
            int b  = nb * 16 + (lane & 15);
            float val = (px < 196) ? x[(b * 3 + v) * 196 + px] : 0.f;
            _Float16 h = (_Float16)val;
            xBv[idx] = __builtin_bit_cast(short, h);
        }
    } else if (part == 4) {
        int w = t >> 6, lane = t & 63;
        for (int b = w; b < 64; b += 4) {
            const float* xp = x + (b * 3 + v) * 196;
            float s = 0.f;
            for (int px = lane; px < 196; px += 64) s = fmaf(xp[px], xp[px], s);
#pragma unroll
            for (int off = 32; off; off >>= 1) s += __shfl_down(s, off, 64);
            if (lane == 0) x2[v * 64 + b] = s;
        }
    } else if (t < 64) {
        int lane = t;
        const float* w2v = w2 + v * 32 * 16 * 9;
        int co = lane & 15;
        int cibase = (lane >> 4) * 8;
#pragma unroll
        for (int tap = 0; tap < 9; ++tap)
#pragma unroll
            for (int j = 0; j < 8; ++j) {
                _Float16 h = (_Float16)w2v[((cibase + j) * 16 + co) * 9 + tap];
                Wf[(((v * 9 + tap) * 64 + lane) << 3) + j] = __builtin_bit_cast(short, h);
            }
    }
}

// ---------------- pmat: P3[v][vc][o] ----------------
__global__ __launch_bounds__(256) void pmat_kernel(const float* __restrict__ le,
                                                   const float* __restrict__ lin_w,
                                                   float* __restrict__ P3) {
    int o  = blockIdx.x * 256 + threadIdx.x;
    int vc = blockIdx.y;
    int v  = blockIdx.z;
    int vp = vc >> 3;
    const float* lwv = lin_w + (size_t)v * 128 * 4096;
    const float* lep = le + vc * 32;
    float acc = 0.f;
#pragma unroll
    for (int e = 0; e < 32; ++e)
        acc = fmaf(lep[e], lwv[(vp * 32 + e) * 4096 + o], acc);
    P3[((size_t)v * 32 + vc) * 4096 + o] = acc;
}

// ---------------- fold1 (ci-halves -> Qa / Qb, plain stores) ----------------
__global__ __launch_bounds__(320) void fold1_kernel(const float* __restrict__ P3,
                                                    const float* __restrict__ lin_b,
                                                    const float* __restrict__ w1,
                                                    const float* __restrict__ b1,
                                                    float* __restrict__ Qa,
                                                    float* __restrict__ Qb) {
    __shared__ float sPt[64 * 144];     // [ci][x_pad 12][y_pad 12], zero-padded
    __shared__ float sW[16 * 32 * 9];
    int row = blockIdx.x;               // 0..32
    int v   = blockIdx.y;               // 0..2
    int z   = blockIdx.z;               // 0..1  ci-half
    int t = threadIdx.x;
    const float* src = (row < 32) ? (P3 + ((size_t)v * 32 + row) * 4096)
                                  : (lin_b + v * 4096);
    float4* zp = (float4*)sPt;
    for (int i = t; i < 2304; i += 320) zp[i] = float4{0.f, 0.f, 0.f, 0.f};
    __syncthreads();
    for (int i = t; i < 4096; i += 320) {
        int ci = i >> 6, r = i & 63, y = r >> 3, xx = r & 7;
        sPt[ci * 144 + (xx + 2) * 12 + (y + 2)] = src[i];
    }
    const float* w1v = w1 + (size_t)v * 64 * 32 * 9;
    int co = t / 10, ox = t % 10;
    float acc[10];
#pragma unroll
    for (int i = 0; i < 10; ++i) acc[i] = 0.f;

    for (int c0 = z * 2; c0 < z * 2 + 2; ++c0) {
        __syncthreads();   // first pass also covers sPt fill
        for (int i = t; i < 4608; i += 320) sW[i] = w1v[c0 * 4608 + i];
        __syncthreads();
#pragma unroll 2
        for (int ci = 0; ci < 16; ++ci) {
            const float* xp = sPt + (c0 * 16 + ci) * 144;
            const float* wp = sW + (ci * 32 + co) * 9;
            float wv[9];
#pragma unroll
            for (int j = 0; j < 9; ++j) wv[j] = wp[j];
#pragma unroll
            for (int b = 0; b < 3; ++b) {
                const float* colp = xp + (ox + 2 - b) * 12;
                float4 c0v = *(const float4*)(colp);
                float4 c1v = *(const float4*)(colp + 4);
                float4 c2v = *(const float4*)(colp + 8);
                float cv[12] = {c0v.x, c0v.y, c0v.z, c0v.w,
                                c1v.x, c1v.y, c1v.z, c1v.w,
                                c2v.x, c2v.y, c2v.z, c2v.w};
#pragma unroll
                for (int a = 0; a < 3; ++a) {
                    float wgt = wv[a * 3 + b];
#pragma unroll
                    for (int oy = 0; oy < 10; ++oy)
                        acc[oy] = fmaf(cv[oy + 2 - a], wgt, acc[oy]);
                }
            }
        }
    }
    float bb = (z == 0 && row == 32) ? b1[v * 32 + co] : 0.f;
    float* dst = (z == 0 ? Qa : Qb) + (size_t)v * 105600 + row * 3200;
#pragma unroll
    for (int oy = 0; oy < 10; ++oy)
        dst[(ox * 10 + oy) * 32 + co] = acc[oy] + bb;
}

// ---------------- pair: Q01[p]=(Qa+Qb)[i0]+(Qa+Qb)[8+i1]; Q23b += bias row ----------------
__global__ __launch_bounds__(256) void pair_kernel(const float* __restrict__ Qa,
                                                   const float* __restrict__ Qb,
                                                   float* __restrict__ Q01,
                                                   float* __restrict__ Q23b) {
    int p = blockIdx.x;        // 0..63
    int half = blockIdx.y;
    int v = blockIdx.z;
    const float4* basea = (const float4*)(Qa + (size_t)v * 105600);
    const float4* baseb = (const float4*)(Qb + (size_t)v * 105600);
    if (half == 0) {
        const float4* ra = basea + (p >> 3) * 800;
        const float4* rb = baseb + (p >> 3) * 800;
        const float4* rc = basea + (8 + (p & 7)) * 800;
        const float4* rd = baseb + (8 + (p & 7)) * 800;
        float4* dst = (float4*)(Q01 + (size_t)v * 204800 + p * 3200);
        for (int i = threadIdx.x; i < 800; i += 256) {
            float4 a = ra[i], b = rb[i], c = rc[i], d = rd[i];
            dst[i] = float4{a.x + b.x + c.x + d.x, a.y + b.y + c.y + d.y,
                            a.z + b.z + c.z + d.z, a.w + b.w + c.w + d.w};
        }
    } else {
        const float4* ra = basea + (16 + (p >> 3)) * 800;
        const float4* rb = baseb + (16 + (p >> 3)) * 800;
        const float4* rc = basea + (24 + (p & 7)) * 800;
        const float4* rd = baseb + (24 + (p & 7)) * 800;
        const float4* re = basea + 32 * 800;
        const float4* rf = baseb + 32 * 800;
        float4* dst = (float4*)(Q23b + (size_t)v * 204800 + p * 3200);
        for (int i = threadIdx.x; i < 800; i += 256) {
            float4 a = ra[i], b = rb[i], c = rc[i], d = rd[i], e = re[i], f = rf[i];
            dst[i] = float4{a.x + b.x + c.x + d.x + e.x + f.x,
                            a.y + b.y + c.y + d.y + e.y + f.y,
                            a.z + b.z + c.z + d.z + e.z + f.z,
                            a.w + b.w + c.w + d.w + e.w + f.w};
        }
    }
}

// ---------------- fused: h1 -> conv2(MFMA f16) -> conv3(dot2) -> Mh,m2 ----------------
__global__ __launch_bounds__(256) void fused_kernel(const float* __restrict__ Q01,   // [3][64][3200]
                                                    const float* __restrict__ Q23b,  // [3][64][3200]
                                                    const short* __restrict__ Wf,    // [3][9][64][8]
                                                    const float* __restrict__ b2,
                                                    const float* __restrict__ w3,    // [3][16][9]
                                                    const float* __restrict__ b3,
                                                    short* __restrict__ Mh,          // [3][4096][224] f16
                                                    float* __restrict__ m2g) {       // [3][4096]
    __shared__ alignas(16) short sH1[196 * 40];  // [pix=c*14+r][40 (32 used)] f16
    __shared__ alignas(16) short sH2[16 * 392];  // c*392 + r*24 + co, f16
    __shared__ int sW3p[72];                     // [tap][ci-pair] packed half2
    __shared__ float sM2;
    int k = blockIdx.x;
    int v = blockIdx.y;
    int t = threadIdx.x;
    int lane = t & 63;
    int g = lane >> 4;

    half8v bfrag[9];
#pragma unroll
    for (int tap = 0; tap < 9; ++tap)
        bfrag[tap] = *(const half8v*)(const void*)(Wf + (((v * 9 + tap) * 64 + lane) << 3));
    float bias2 = b2[v * 16 + (lane & 15)];

    if (t == 0) sM2 = 0.f;
    for (int pix = t; pix < 196; pix += 256) {
        int c = pix / 14, r = pix % 14;
        if (c < 2 || c >= 12 || r < 2 || r >= 12) {
            int4* z = (int4*)(sH1 + pix * 40);
            z[0] = int4{0,0,0,0}; z[1] = int4{0,0,0,0};
            z[2] = int4{0,0,0,0}; z[3] = int4{0,0,0,0};
        }
    }
    {
        int pix = t;
        int c = pix >> 4, r = pix & 15;
        if (c < 2 || c >= 14 || r < 2 || r >= 14) {
            int4* z = (int4*)(sH2 + c * 392 + r * 24);
            z[0] = int4{0,0,0,0}; z[1] = int4{0,0,0,0};
        }
    }
    if (t < 72) {
        int tap = t / 8, j = t % 8;
        half2v p = {(_Float16)w3[v * 144 + (2 * j) * 9 + tap],
                    (_Float16)w3[v * 144 + (2 * j + 1) * 9 + tap]};
        sW3p[t] = __builtin_bit_cast(int, p);
    }

    // phase 1: h1 = ELU(Q01 + Q23b) -> sH1 (f16)
    {
        const float4* qa = (const float4*)(Q01  + ((size_t)v * 64 + (k >> 6)) * 3200);
        const float4* qb = (const float4*)(Q23b + ((size_t)v * 64 + (k & 63)) * 3200);
        int ci4 = (t & 7) * 4;
        int pix = t >> 3;               // steps by 32
        int cx = pix / 10, ry = pix % 10;
        for (int i = t; i < 800; i += 256) {
            float4 a = qa[i], b = qb[i];
            half4v o = {(_Float16)elu(a.x + b.x), (_Float16)elu(a.y + b.y),
                        (_Float16)elu(a.z + b.z), (_Float16)elu(a.w + b.w)};
            *(half4v*)(void*)(sH1 + ((cx + 2) * 14 + (ry + 2)) * 40 + ci4) = o;
            cx += 3; ry += 2;
            if (ry >= 10) { ry -= 10; ++cx; }
        }
    }
    __syncthreads();

    // phase 2: conv2 via MFMA f16, dual accumulators
    {
        int w = t >> 6;
        for (int tile = w; tile < 9; tile += 4) {
            int m = tile * 16 + (lane & 15);
            int cx2 = m / 12, ry2 = m % 12;
            const short* basemin = sH1 + (cx2 * 14 + ry2) * 40 + g * 8;
            f32x4 acc0 = {bias2, bias2, bias2, bias2};
            f32x4 acc1 = {0.f, 0.f, 0.f, 0.f};
#pragma unroll
            for (int a = 0; a < 3; ++a)
#pragma unroll
                for (int b = 0; b < 3; ++b) {
                    half8v af = *(const half8v*)(const void*)(basemin + ((2 - b) * 14 + (2 - a)) * 40);
                    int idx = a * 3 + b;
                    if (idx & 1)
                        acc1 = __builtin_amdgcn_mfma_f32_16x16x32_f16(af, bfrag[idx], acc1, 0, 0, 0);
                    else
                        acc0 = __builtin_amdgcn_mfma_f32_16x16x32_f16(af, bfrag[idx], acc0, 0, 0, 0);
                }
            int p0 = tile * 16 + g * 4;
            int cxp = p0 / 12, ryp = p0 % 12;
            int co = lane & 15;
#pragma unroll
            for (int r = 0; r < 4; ++r) {
                _Float16 h = (_Float16)elu(acc0[r] + acc1[r]);
                sH2[(cxp + 2) * 392 + (ryp + 2) * 24 + co] = __builtin_bit_cast(short, h);
                ++ryp; if (ryp == 12) { ryp = 0; ++cxp; }
            }
        }
    }
    __syncthreads();

    // phase 3: conv3 via v_dot2_f32_f16 -> Mh f16 + m2 reduction
    {
        float mval = 0.f;
        if (t < 196) {
            float bias3 = b3[v];
            int ry3 = t / 14, cx3 = t % 14;
            float a0 = bias3, a1 = 0.f, a2 = 0.f, a3 = 0.f;
#pragma unroll
            for (int a = 0; a < 3; ++a)
#pragma unroll
                for (int b = 0; b < 3; ++b) {
                    const short* base = sH2 + (cx3 + 2 - b) * 392 + (ry3 + 2 - a) * 24;
                    int4 lo = *(const int4*)(const void*)(base);
                    int4 hi = *(const int4*)(const void*)(base + 8);
                    const int* wp = sW3p + (a * 3 + b) * 8;
                    a0 = dot2acc(lo.x, wp[0], a0);
                    a1 = dot2acc(lo.y, wp[1], a1);
                    a2 = dot2acc(lo.z, wp[2], a2);
                    a3 = dot2acc(lo.w, wp[3], a3);
                    a0 = dot2acc(hi.x, wp[4], a0);
                    a1 = dot2acc(hi.y, wp[5], a1);
                    a2 = dot2acc(hi.z, wp[6], a2);
                    a3 = dot2acc(hi.w, wp[7], a3);
                }
            mval = (a0 + a1) + (a2 + a3);
        }
        if (t < 224) {
            _Float16 h = (_Float16)mval;
            Mh[((size_t)v * 4096 + k) * 224 + t] = __builtin_bit_cast(short, h);
        }
        float sq = mval * mval;
#pragma unroll
        for (int off = 32; off; off >>= 1) sq += __shfl_down(sq, off, 64);
        if (lane == 0) atomicAdd(&sM2, sq);
        __syncthreads();
        if (t == 0) m2g[(size_t)v * 4096 + k] = sM2;
    }
}

// ---------------- gemm_final: cross via MFMA; out[b][k][v] ----------------
__global__ __launch_bounds__(256) void gemm_final_kernel(const short* __restrict__ Mh,   // [3][4096][224]
                                                         const short* __restrict__ xB,   // [3][4][7][64][8]
                                                         const float* __restrict__ m2g,  // [3][4096]
                                                         const float* __restrict__ x2g,  // [3][64]
                                                         float* __restrict__ out) {      // [64][4096][3]
    __shared__ float sC[3 * 64 * 17];
    __shared__ float sM2t[48];
    int t = threadIdx.x, lane = t & 63, nb = t >> 6;
    int k0 = blockIdx.x * 16;
    if (t < 48) {
        int v = t % 3, kk = t / 3;
        sM2t[kk * 3 + v] = m2g[(size_t)v * 4096 + k0 + kk];
    }
    int mrow = lane & 15;
    int g = lane >> 4;
#pragma unroll
    for (int v = 0; v < 3; ++v) {
        f32x4 acc = {0.f, 0.f, 0.f, 0.f};
        const short* abase = Mh + ((size_t)v * 4096 + k0 + mrow) * 224 + g * 8;
        const short* bbase = xB + (((v * 4 + nb) * 7) * 64 + lane) * 8;
#pragma unroll
        for (int s = 0; s < 7; ++s) {
            half8v af = *(const half8v*)(const void*)(abase + s * 32);
            half8v bf = *(const half8v*)(const void*)(bbase + s * 512);
            acc = __builtin_amdgcn_mfma_f32_16x16x32_f16(af, bf, acc, 0, 0, 0);
        }
        int b = nb * 16 + mrow;     // D col = lane&15
#pragma unroll
        for (int r = 0; r < 4; ++r)
            sC[(v * 64 + b) * 17 + g * 4 + r] = acc[r];
    }
    __syncthreads();
    int b = t >> 2, q = t & 3;
    float x2v0 = x2g[b], x2v1 = x2g[64 + b], x2v2 = x2g[128 + b];
    float buf[12];
#pragma unroll
    for (int i = 0; i < 4; ++i) {
        int kk = q * 4 + i;
        buf[i * 3 + 0] = sC[(0 * 64 + b) * 17 + kk] - 0.5f * (sM2t[kk * 3 + 0] + x2v0);
        buf[i * 3 + 1] = sC[(1 * 64 + b) * 17 + kk] - 0.5f * (sM2t[kk * 3 + 1] + x2v1);
        buf[i * 3 + 2] = sC[(2 * 64 + b) * 17 + kk] - 0.5f * (sM2t[kk * 3 + 2] + x2v2);
    }
    float* dst = out + ((size_t)b * 4096 + k0) * 3 + q * 12;
    *(float4*)(dst)     = float4{buf[0], buf[1], buf[2],  buf[3]};
    *(float4*)(dst + 4) = float4{buf[4], buf[5], buf[6],  buf[7]};
    *(float4*)(dst + 8) = float4{buf[8], buf[9], buf[10], buf[11]};
}

extern "C" void kernel_launch(void* const* d_in, const int* in_sizes, int n_in,
                              void* d_out, int out_size, void* d_ws, size_t ws_size,
                              hipStream_t stream) {
    const float* x     = (const float*)d_in[0];
    const float* le    = (const float*)d_in[1];
    const float* lin_w = (const float*)d_in[2];
    const float* lin_b = (const float*)d_in[3];
    const float* w1    = (const float*)d_in[4];
    const float* b1    = (const float*)d_in[5];
    const float* w2    = (const float*)d_in[6];
    const float* b2    = (const float*)d_in[7];
    const float* w3    = (const float*)d_in[8];
    const float* b3    = (const float*)d_in[9];
    float* out = (float*)d_out;

    float* ws = (float*)d_ws;
    // workspace (floats):
    float* x2g  = ws;                        // 192
    short* xB   = (short*)(ws + 192);        // 43008 shorts = 21504 floats
    short* Wf   = (short*)(ws + 21760);      // 13824 shorts = 6912 floats
    float* P3   = ws + 28736;                // 393216
    float* Qa   = ws + 421952;               // 316800
    float* Qb   = ws + 738752;               // 316800
    float* Q01  = ws + 1055552;              // 614400
    float* Q23b = ws + 1669952;              // 614400
    short* Mh   = (short*)(ws + 2284352);    // 2752512 shorts = 1376256 floats
    float* m2g  = ws + 3660608;              // 12288

    pre_kernel<<<dim3(3, 6), 256, 0, stream>>>(x, x2g, xB, w2, Wf);
    pmat_kernel<<<dim3(16, 32, 3), 256, 0, stream>>>(le, lin_w, P3);
    fold1_kernel<<<dim3(33, 3, 2), 320, 0, stream>>>(P3, lin_b, w1, b1, Qa, Qb);
    pair_kernel<<<dim3(64, 2, 3), 256, 0, stream>>>(Qa, Qb, Q01, Q23b);
    fused_kernel<<<dim3(4096, 3), 256, 0, stream>>>(Q01, Q23b, Wf, b2, w3, b3, Mh, m2g);
    gemm_final_kernel<<<256, 256, 0, stream>>>(Mh, xB, m2g, x2g, out);
}

// Round 9
// 180.630 us; speedup vs baseline: 12.7923x; 1.1058x over previous
//
#include <hip/hip_runtime.h>
#include <cstddef>

// CS=8 NV=4 ED=32 VIEWS=3 D=16 KSZ=3 HW=14 CSP=8 KSTATES=4096
// Pipeline (4 launches):
//   prep: blocks 0..197 = fold1 role (inline P row -> conv_t1 -> Qa/Qb halves)
//         blocks 198..215 = pre roles (xB frags, x2, Wf)
//   pair: Q01/Q23b[3][64][3200] pairwise digit sums
//   fused per (state,view), 256 thr: h1=ELU(Q01+Q23b) -> f16 LDS
//     -> conv2 = 81x mfma_f32_16x16x32_f16 -> ELU -> f16 LDS (swizzled)
//     -> conv3 via v_dot2_f32_f16 -> Mh[v][k][224] f16 + m2[v][k]
//   gemm_final: cross = Mh x xB via MFMA f16; out = cross -.5(m2+x2)
// sH2 swizzle: addr = col*392 + row*24 + ((row>>2)&3)*8  — puts the 4
// ci-group store clusters at bank bases {0,20,8,28} (was {0,16,0,16} 8-way).

typedef __attribute__((ext_vector_type(4))) float f32x4;
typedef _Float16 half8v __attribute__((ext_vector_type(8)));
typedef _Float16 half4v __attribute__((ext_vector_type(4)));
typedef _Float16 half2v __attribute__((ext_vector_type(2)));

static __device__ __forceinline__ float elu(float s) {
    float e = __expf(s) - 1.0f;
    return s > 0.f ? s : e;
}
static __device__ __forceinline__ float dot2acc(int hpair, int wpair, float acc) {
#if __has_builtin(__builtin_amdgcn_fdot2)
    return __builtin_amdgcn_fdot2(__builtin_bit_cast(half2v, hpair),
                                  __builtin_bit_cast(half2v, wpair), acc, false);
#else
    half2v h = __builtin_bit_cast(half2v, hpair);
    half2v w = __builtin_bit_cast(half2v, wpair);
    acc = fmaf((float)h.x, (float)w.x, acc);
    return fmaf((float)h.y, (float)w.y, acc);
#endif
}
static __device__ __forceinline__ int sh2addr(int c, int r) {
    return c * 392 + r * 24 + (((r >> 2) & 3) << 3);
}

// ---------------- prep: fold1 roles (0..197) + pre roles (198..215) ----------------
__global__ __launch_bounds__(320) void prep_kernel(const float* __restrict__ x,
                                                   const float* __restrict__ le,
                                                   const float* __restrict__ lin_w,
                                                   const float* __restrict__ lin_b,
                                                   const float* __restrict__ w1,
                                                   const float* __restrict__ b1,
                                                   const float* __restrict__ w2,
                                                   float* __restrict__ Qa,
                                                   float* __restrict__ Qb,
                                                   float* __restrict__ x2,
                                                   short* __restrict__ xB,
                                                   short* __restrict__ Wf) {
    int bid = blockIdx.x;
    int t = threadIdx.x;
    if (bid >= 198) {
        // ---- pre roles ----
        int pid = bid - 198;
        int v = pid % 3, part = pid / 3;
        if (part < 4) {
            int nb = part;
            short* xBv = xB + v * 14336 + nb * 3584;
            for (int idx = t; idx < 3584; idx += 320) {
                int j = idx & 7, lane = (idx >> 3) & 63, s = idx >> 9;
                int px = s * 32 + ((lane >> 4) << 3) + j;
                int b  = nb * 16 + (lane & 15);
                float val = (px < 196) ? x[(b * 3 + v) * 196 + px] : 0.f;
                _Float16 h = (_Float16)val;
                xBv[idx] = __builtin_bit_cast(short, h);
            }
        } else if (part == 4) {
            int w = t >> 6, lane = t & 63;
            for (int b = w; b < 64; b += 5) {
                const float* xp = x + (b * 3 + v) * 196;
                float s = 0.f;
                for (int px = lane; px < 196; px += 64) s = fmaf(xp[px], xp[px], s);
#pragma unroll
                for (int off = 32; off; off >>= 1) s += __shfl_down(s, off, 64);
                if (lane == 0) x2[v * 64 + b] = s;
            }
        } else if (t < 64) {
            int lane = t;
            const float* w2v = w2 + v * 32 * 16 * 9;
            int co = lane & 15;
            int cibase = (lane >> 4) * 8;
#pragma unroll
            for (int tap = 0; tap < 9; ++tap)
#pragma unroll
                for (int j = 0; j < 8; ++j) {
                    _Float16 h = (_Float16)w2v[((cibase + j) * 16 + co) * 9 + tap];
                    Wf[(((v * 9 + tap) * 64 + lane) << 3) + j] = __builtin_bit_cast(short, h);
                }
        }
        return;
    }
    // ---- fold1 role: (row, v, z) ----
    __shared__ float sPt[64 * 144];     // [ci][x_pad 12][y_pad 12], zero-padded
    __shared__ float sW[16 * 32 * 9];
    int row = bid % 33;
    int v   = (bid / 33) % 3;
    int z   = bid / 99;

    // inline P row (replaces pmat kernel): 256 threads x 16 outputs
    float pacc[16];
    if (t < 256) {
        if (row < 32) {
            int vp = row >> 3;
            const float* base0 = lin_w + (size_t)v * 524288 + (size_t)vp * 32 * 4096 + t;
            const float* lep = le + row * 32;
#pragma unroll
            for (int j = 0; j < 16; ++j) pacc[j] = 0.f;
            for (int e = 0; e < 32; ++e) {
                float lv = lep[e];
                const float* bp = base0 + e * 4096;
#pragma unroll
                for (int j = 0; j < 16; ++j)
                    pacc[j] = fmaf(lv, bp[j * 256], pacc[j]);
            }
        } else {
            const float* bp = lin_b + v * 4096 + t;
#pragma unroll
            for (int j = 0; j < 16; ++j) pacc[j] = bp[j * 256];
        }
    }
    float4* zp = (float4*)sPt;
    for (int i = t; i < 2304; i += 320) zp[i] = float4{0.f, 0.f, 0.f, 0.f};
    __syncthreads();
    if (t < 256) {
#pragma unroll
        for (int j = 0; j < 16; ++j) {
            int i = t + j * 256;
            int ci = i >> 6, r = i & 63, y = r >> 3, xx = r & 7;
            sPt[ci * 144 + (xx + 2) * 12 + (y + 2)] = pacc[j];
        }
    }
    const float* w1v = w1 + (size_t)v * 64 * 32 * 9;
    int co = t / 10, ox = t % 10;
    float acc[10];
#pragma unroll
    for (int i = 0; i < 10; ++i) acc[i] = 0.f;

    for (int c0 = z * 2; c0 < z * 2 + 2; ++c0) {
        __syncthreads();   // first pass also covers sPt fill
        for (int i = t; i < 4608; i += 320) sW[i] = w1v[c0 * 4608 + i];
        __syncthreads();
#pragma unroll 2
        for (int ci = 0; ci < 16; ++ci) {
            const float* xp = sPt + (c0 * 16 + ci) * 144;
            const float* wp = sW + (ci * 32 + co) * 9;
            float wv[9];
#pragma unroll
            for (int j = 0; j < 9; ++j) wv[j] = wp[j];
#pragma unroll
            for (int b = 0; b < 3; ++b) {
                const float* colp = xp + (ox + 2 - b) * 12;
                float4 c0v = *(const float4*)(colp);
                float4 c1v = *(const float4*)(colp + 4);
                float4 c2v = *(const float4*)(colp + 8);
                float cv[12] = {c0v.x, c0v.y, c0v.z, c0v.w,
                                c1v.x, c1v.y, c1v.z, c1v.w,
                                c2v.x, c2v.y, c2v.z, c2v.w};
#pragma unroll
                for (int a = 0; a < 3; ++a) {
                    float wgt = wv[a * 3 + b];
#pragma unroll
                    for (int oy = 0; oy < 10; ++oy)
                        acc[oy] = fmaf(cv[oy + 2 - a], wgt, acc[oy]);
                }
            }
        }
    }
    float bb = (z == 0 && row == 32) ? b1[v * 32 + co] : 0.f;
    float* dst = (z == 0 ? Qa : Qb) + (size_t)v * 105600 + row * 3200;
#pragma unroll
    for (int oy = 0; oy < 10; ++oy)
        dst[(ox * 10 + oy) * 32 + co] = acc[oy] + bb;
}

// ---------------- pair: Q01[p]=(Qa+Qb)[i0]+(Qa+Qb)[8+i1]; Q23b += bias row ----------------
__global__ __launch_bounds__(256) void pair_kernel(const float* __restrict__ Qa,
                                                   const float* __restrict__ Qb,
                                                   float* __restrict__ Q01,
                                                   float* __restrict__ Q23b) {
    int p = blockIdx.x;        // 0..63
    int half = blockIdx.y;
    int v = blockIdx.z;
    const float4* basea = (const float4*)(Qa + (size_t)v * 105600);
    const float4* baseb = (const float4*)(Qb + (size_t)v * 105600);
    if (half == 0) {
        const float4* ra = basea + (p >> 3) * 800;
        const float4* rb = baseb + (p >> 3) * 800;
        const float4* rc = basea + (8 + (p & 7)) * 800;
        const float4* rd = baseb + (8 + (p & 7)) * 800;
        float4* dst = (float4*)(Q01 + (size_t)v * 204800 + p * 3200);
        for (int i = threadIdx.x; i < 800; i += 256) {
            float4 a = ra[i], b = rb[i], c = rc[i], d = rd[i];
            dst[i] = float4{a.x + b.x + c.x + d.x, a.y + b.y + c.y + d.y,
                            a.z + b.z + c.z + d.z, a.w + b.w + c.w + d.w};
        }
    } else {
        const float4* ra = basea + (16 + (p >> 3)) * 800;
        const float4* rb = baseb + (16 + (p >> 3)) * 800;
        const float4* rc = basea + (24 + (p & 7)) * 800;
        const float4* rd = baseb + (24 + (p & 7)) * 800;
        const float4* re = basea + 32 * 800;
        const float4* rf = baseb + 32 * 800;
        float4* dst = (float4*)(Q23b + (size_t)v * 204800 + p * 3200);
        for (int i = threadIdx.x; i < 800; i += 256) {
            float4 a = ra[i], b = rb[i], c = rc[i], d = rd[i], e = re[i], f = rf[i];
            dst[i] = float4{a.x + b.x + c.x + d.x + e.x + f.x,
                            a.y + b.y + c.y + d.y + e.y + f.y,
                            a.z + b.z + c.z + d.z + e.z + f.z,
                            a.w + b.w + c.w + d.w + e.w + f.w};
        }
    }
}

// ---------------- fused: h1 -> conv2(MFMA f16) -> conv3(dot2) -> Mh,m2 ----------------
__global__ __launch_bounds__(256) void fused_kernel(const float* __restrict__ Q01,   // [3][64][3200]
                                                    const float* __restrict__ Q23b,  // [3][64][3200]
                                                    const short* __restrict__ Wf,    // [3][9][64][8]
                                                    const float* __restrict__ b2,
                                                    const float* __restrict__ w3,    // [3][16][9]
                                                    const float* __restrict__ b3,
                                                    short* __restrict__ Mh,          // [3][4096][224] f16
                                                    float* __restrict__ m2g) {       // [3][4096]
    __shared__ alignas(16) short sH1[196 * 40];  // [pix=c*14+r][40 (32 used)] f16
    __shared__ alignas(16) short sH2[6280];      // swizzled: sh2addr(c,r)+co, f16
    __shared__ int sW3p[72];                     // [tap][ci-pair] packed half2
    __shared__ float sM2;
    int k = blockIdx.x;
    int v = blockIdx.y;
    int t = threadIdx.x;
    int lane = t & 63;
    int g = lane >> 4;

    half8v bfrag[9];
#pragma unroll
    for (int tap = 0; tap < 9; ++tap)
        bfrag[tap] = *(const half8v*)(const void*)(Wf + (((v * 9 + tap) * 64 + lane) << 3));
    float bias2 = b2[v * 16 + (lane & 15)];

    if (t == 0) sM2 = 0.f;
    for (int pix = t; pix < 196; pix += 256) {
        int c = pix / 14, r = pix % 14;
        if (c < 2 || c >= 12 || r < 2 || r >= 12) {
            int4* z = (int4*)(sH1 + pix * 40);
            z[0] = int4{0,0,0,0}; z[1] = int4{0,0,0,0};
            z[2] = int4{0,0,0,0}; z[3] = int4{0,0,0,0};
        }
    }
    {
        int pix = t;
        int c = pix >> 4, r = pix & 15;
        if (c < 2 || c >= 14 || r < 2 || r >= 14) {
            int4* z = (int4*)(sH2 + sh2addr(c, r));
            z[0] = int4{0,0,0,0}; z[1] = int4{0,0,0,0};
        }
    }
    if (t < 72) {
        int tap = t / 8, j = t % 8;
        half2v p = {(_Float16)w3[v * 144 + (2 * j) * 9 + tap],
                    (_Float16)w3[v * 144 + (2 * j + 1) * 9 + tap]};
        sW3p[t] = __builtin_bit_cast(int, p);
    }

    // phase 1: h1 = ELU(Q01 + Q23b) -> sH1 (f16)
    {
        const float4* qa = (const float4*)(Q01  + ((size_t)v * 64 + (k >> 6)) * 3200);
        const float4* qb = (const float4*)(Q23b + ((size_t)v * 64 + (k & 63)) * 3200);
        int ci4 = (t & 7) * 4;
        int pix = t >> 3;               // steps by 32
        int cx = pix / 10, ry = pix % 10;
        for (int i = t; i < 800; i += 256) {
            float4 a = qa[i], b = qb[i];
            half4v o = {(_Float16)elu(a.x + b.x), (_Float16)elu(a.y + b.y),
                        (_Float16)elu(a.z + b.z), (_Float16)elu(a.w + b.w)};
            *(half4v*)(void*)(sH1 + ((cx + 2) * 14 + (ry + 2)) * 40 + ci4) = o;
            cx += 3; ry += 2;
            if (ry >= 10) { ry -= 10; ++cx; }
        }
    }
    __syncthreads();

    // phase 2: conv2 via MFMA f16, dual accumulators
    {
        int w = t >> 6;
        for (int tile = w; tile < 9; tile += 4) {
            int m = tile * 16 + (lane & 15);
            int cx2 = m / 12, ry2 = m % 12;
            const short* basemin = sH1 + (cx2 * 14 + ry2) * 40 + g * 8;
            f32x4 acc0 = {bias2, bias2, bias2, bias2};
            f32x4 acc1 = {0.f, 0.f, 0.f, 0.f};
#pragma unroll
            for (int a = 0; a < 3; ++a)
#pragma unroll
                for (int b = 0; b < 3; ++b) {
                    half8v af = *(const half8v*)(const void*)(basemin + ((2 - b) * 14 + (2 - a)) * 40);
                    int idx = a * 3 + b;
                    if (idx & 1)
                        acc1 = __builtin_amdgcn_mfma_f32_16x16x32_f16(af, bfrag[idx], acc1, 0, 0, 0);
                    else
                        acc0 = __builtin_amdgcn_mfma_f32_16x16x32_f16(af, bfrag[idx], acc0, 0, 0, 0);
                }
            int p0 = tile * 16 + g * 4;
            int cxp = p0 / 12, ryp = p0 % 12;
            int co = lane & 15;
#pragma unroll
            for (int r = 0; r < 4; ++r) {
                _Float16 h = (_Float16)elu(acc0[r] + acc1[r]);
                sH2[sh2addr(cxp + 2, ryp + 2) + co] = __builtin_bit_cast(short, h);
                ++ryp; if (ryp == 12) { ryp = 0; ++cxp; }
            }
        }
    }
    __syncthreads();

    // phase 3: conv3 via v_dot2_f32_f16 -> Mh f16 + m2 reduction
    {
        float mval = 0.f;
        if (t < 196) {
            float bias3 = b3[v];
            int ry3 = t / 14, cx3 = t % 14;
            float a0 = bias3, a1 = 0.f, a2 = 0.f, a3 = 0.f;
#pragma unroll
            for (int a = 0; a < 3; ++a)
#pragma unroll
                for (int b = 0; b < 3; ++b) {
                    const short* base = sH2 + sh2addr(cx3 + 2 - b, ry3 + 2 - a);
                    int4 lo = *(const int4*)(const void*)(base);
                    int4 hi = *(const int4*)(const void*)(base + 8);
                    const int* wp = sW3p + (a * 3 + b) * 8;
                    a0 = dot2acc(lo.x, wp[0], a0);
                    a1 = dot2acc(lo.y, wp[1], a1);
                    a2 = dot2acc(lo.z, wp[2], a2);
                    a3 = dot2acc(lo.w, wp[3], a3);
                    a0 = dot2acc(hi.x, wp[4], a0);
                    a1 = dot2acc(hi.y, wp[5], a1);
                    a2 = dot2acc(hi.z, wp[6], a2);
                    a3 = dot2acc(hi.w, wp[7], a3);
                }
            mval = (a0 + a1) + (a2 + a3);
        }
        if (t < 224) {
            _Float16 h = (_Float16)mval;
            Mh[((size_t)v * 4096 + k) * 224 + t] = __builtin_bit_cast(short, h);
        }
        float sq = mval * mval;
#pragma unroll
        for (int off = 32; off; off >>= 1) sq += __shfl_down(sq, off, 64);
        if (lane == 0) atomicAdd(&sM2, sq);
        __syncthreads();
        if (t == 0) m2g[(size_t)v * 4096 + k] = sM2;
    }
}

// ---------------- gemm_final: cross via MFMA; out[b][k][v] ----------------
__global__ __launch_bounds__(256) void gemm_final_kernel(const short* __restrict__ Mh,   // [3][4096][224]
                                                         const short* __restrict__ xB,   // [3][4][7][64][8]
                                                         const float* __restrict__ m2g,  // [3][4096]
                                                         const float* __restrict__ x2g,  // [3][64]
                                                         float* __restrict__ out) {      // [64][4096][3]
    __shared__ float sC[3 * 64 * 17];
    __shared__ float sM2t[48];
    int t = threadIdx.x, lane = t & 63, nb = t >> 6;
    int k0 = blockIdx.x * 16;
    if (t < 48) {
        int v = t % 3, kk = t / 3;
        sM2t[kk * 3 + v] = m2g[(size_t)v * 4096 + k0 + kk];
    }
    int mrow = lane & 15;
    int g = lane >> 4;
#pragma unroll
    for (int v = 0; v < 3; ++v) {
        f32x4 acc = {0.f, 0.f, 0.f, 0.f};
        const short* abase = Mh + ((size_t)v * 4096 + k0 + mrow) * 224 + g * 8;
        const short* bbase = xB + (((v * 4 + nb) * 7) * 64 + lane) * 8;
#pragma unroll
        for (int s = 0; s < 7; ++s) {
            half8v af = *(const half8v*)(const void*)(abase + s * 32);
            half8v bf = *(const half8v*)(const void*)(bbase + s * 512);
            acc = __builtin_amdgcn_mfma_f32_16x16x32_f16(af, bf, acc, 0, 0, 0);
        }
        int b = nb * 16 + mrow;     // D col = lane&15
#pragma unroll
        for (int r = 0; r < 4; ++r)
            sC[(v * 64 + b) * 17 + g * 4 + r] = acc[r];
    }
    __syncthreads();
    int b = t >> 2, q = t & 3;
    float x2v0 = x2g[b], x2v1 = x2g[64 + b], x2v2 = x2g[128 + b];
    float buf[12];
#pragma unroll
    for (int i = 0; i < 4; ++i) {
        int kk = q * 4 + i;
        buf[i * 3 + 0] = sC[(0 * 64 + b) * 17 + kk] - 0.5f * (sM2t[kk * 3 + 0] + x2v0);
        buf[i * 3 + 1] = sC[(1 * 64 + b) * 17 + kk] - 0.5f * (sM2t[kk * 3 + 1] + x2v1);
        buf[i * 3 + 2] = sC[(2 * 64 + b) * 17 + kk] - 0.5f * (sM2t[kk * 3 + 2] + x2v2);
    }
    float* dst = out + ((size_t)b * 4096 + k0) * 3 + q * 12;
    *(float4*)(dst)     = float4{buf[0], buf[1], buf[2],  buf[3]};
    *(float4*)(dst + 4) = float4{buf[4], buf[5], buf[6],  buf[7]};
    *(float4*)(dst + 8) = float4{buf[8], buf[9], buf[10], buf[11]};
}

extern "C" void kernel_launch(void* const* d_in, const int* in_sizes, int n_in,
                              void* d_out, int out_size, void* d_ws, size_t ws_size,
                              hipStream_t stream) {
    const float* x     = (const float*)d_in[0];
    const float* le    = (const float*)d_in[1];
    const float* lin_w = (const float*)d_in[2];
    const float* lin_b = (const float*)d_in[3];
    const float* w1    = (const float*)d_in[4];
    const float* b1    = (const float*)d_in[5];
    const float* w2    = (const float*)d_in[6];
    const float* b2    = (const float*)d_in[7];
    const float* w3    = (const float*)d_in[8];
    const float* b3    = (const float*)d_in[9];
    float* out = (float*)d_out;

    float* ws = (float*)d_ws;
    // workspace (floats):
    float* x2g  = ws;                        // 192
    short* xB   = (short*)(ws + 192);        // 43008 shorts = 21504 floats
    short* Wf   = (short*)(ws + 21760);      // 13824 shorts = 6912 floats
    float* Qa   = ws + 28736;                // 316800
    float* Qb   = ws + 345536;               // 316800
    float* Q01  = ws + 662336;               // 614400
    float* Q23b = ws + 1276736;              // 614400
    short* Mh   = (short*)(ws + 1891136);    // 2752512 shorts = 1376256 floats
    float* m2g  = ws + 3267392;              // 12288

    prep_kernel<<<216, 320, 0, stream>>>(x, le, lin_w, lin_b, w1, b1, w2,
                                         Qa, Qb, x2g, xB, Wf);
    pair_kernel<<<dim3(64, 2, 3), 256, 0, stream>>>(Qa, Qb, Q01, Q23b);
    fused_kernel<<<dim3(4096, 3), 256, 0, stream>>>(Q01, Q23b, Wf, b2, w3, b3, Mh, m2g);
    gemm_final_kernel<<<256, 256, 0, stream>>>(Mh, xB, m2g, x2g, out);
}